// Round 1
// baseline (444.333 us; speedup 1.0000x reference)
//
#include <hip/hip_runtime.h>
#include <stdint.h>
#include <stddef.h>

#define N_TOK 4096
#define DM    1024
#define NHEAD 16
#define HD    64

typedef __attribute__((ext_vector_type(8))) short  bf16x8;
typedef __attribute__((ext_vector_type(4))) short  bf16x4;
typedef __attribute__((ext_vector_type(4))) float  f32x4;

static __device__ __forceinline__ float bf2f(short u) {
  union { unsigned int i; float f; } c;
  c.i = ((unsigned int)(unsigned short)u) << 16;
  return c.f;
}
static __device__ __forceinline__ unsigned short f2bf(float f) {
  union { float f; unsigned int i; } c; c.f = f;
  unsigned int x = c.i;
  return (unsigned short)((x + 0x7fffu + ((x >> 16) & 1u)) >> 16);
}

// async global->LDS, 16B per lane. LDS dest must be wave-uniform base (HW adds lane*16).
static __device__ __forceinline__ void gload16(const void* g, void* l) {
  __builtin_amdgcn_global_load_lds(
      (const __attribute__((address_space(1))) unsigned int*)g,
      (__attribute__((address_space(3))) unsigned int*)l, 16, 0, 0);
}

// ---------------- fp32 -> bf16 conversion ----------------
__global__ void cvt_kernel(const float* __restrict__ src,
                           unsigned short* __restrict__ dst, int n8) {
  int i = blockIdx.x * blockDim.x + threadIdx.x;
  int stride = gridDim.x * blockDim.x;
  for (; i < n8; i += stride) {
    const f32x4* s = (const f32x4*)(src + (size_t)i * 8);
    f32x4 a = s[0], b = s[1];
    bf16x8 o;
    o[0] = (short)f2bf(a[0]); o[1] = (short)f2bf(a[1]);
    o[2] = (short)f2bf(a[2]); o[3] = (short)f2bf(a[3]);
    o[4] = (short)f2bf(b[0]); o[5] = (short)f2bf(b[1]);
    o[6] = (short)f2bf(b[2]); o[7] = (short)f2bf(b[3]);
    *(bf16x8*)(dst + (size_t)i * 8) = o;
  }
}

// ---------------- C = A @ W^T + bias  (m97-style 128x128 tile) ----------------
// A: MxK bf16 row-major, W: NxK bf16 row-major. out_f32 ? Cf fp32 : Cb bf16.
__global__ __launch_bounds__(256) void gemm_bt(
    const unsigned short* __restrict__ A,
    const unsigned short* __restrict__ W,
    const float* __restrict__ bias,
    unsigned short* __restrict__ Cb,
    float* __restrict__ Cf,
    int M, int Nn, int K, int out_f32)
{
  __shared__ __align__(16) unsigned short At[128 * 32];
  __shared__ __align__(16) unsigned short Wt[128 * 32];
  const int tid  = threadIdx.x;
  const int wid  = tid >> 6, lane = tid & 63;
  const int lm   = lane & 15, lg = lane >> 4;
  const int m0   = blockIdx.y * 128, n0 = blockIdx.x * 128;
  const int wm   = (wid >> 1) * 64,  wn = (wid & 1) * 64;

  f32x4 acc[4][4];
#pragma unroll
  for (int i = 0; i < 4; ++i)
#pragma unroll
    for (int j = 0; j < 4; ++j) acc[i][j] = f32x4{0.f, 0.f, 0.f, 0.f};

  for (int k0 = 0; k0 < K; k0 += 32) {
    __syncthreads();   // previous iteration's LDS reads done
#pragma unroll
    for (int i = 0; i < 2; ++i) {
      int ca = wid * 64 + lane + i * 256;          // chunk id 0..511
      gload16(A + (size_t)(m0 + (ca >> 2)) * K + (k0 + (ca & 3) * 8),
              (char*)At + (size_t)(wid * 64 + i * 256) * 16);
      gload16(W + (size_t)(n0 + (ca >> 2)) * K + (k0 + (ca & 3) * 8),
              (char*)Wt + (size_t)(wid * 64 + i * 256) * 16);
    }
    __syncthreads();   // staging complete (vmcnt drained by barrier)

    bf16x8 af[4], bfr[4];
#pragma unroll
    for (int mi = 0; mi < 4; ++mi)
      af[mi] = *(const bf16x8*)&At[(wm + mi * 16 + lm) * 32 + lg * 8];
#pragma unroll
    for (int ni = 0; ni < 4; ++ni)
      bfr[ni] = *(const bf16x8*)&Wt[(wn + ni * 16 + lm) * 32 + lg * 8];
#pragma unroll
    for (int mi = 0; mi < 4; ++mi)
#pragma unroll
      for (int ni = 0; ni < 4; ++ni)
        acc[mi][ni] = __builtin_amdgcn_mfma_f32_16x16x32_bf16(
            af[mi], bfr[ni], acc[mi][ni], 0, 0, 0);
  }

  float bv[4];
#pragma unroll
  for (int ni = 0; ni < 4; ++ni) bv[ni] = bias[n0 + wn + ni * 16 + lm];
#pragma unroll
  for (int mi = 0; mi < 4; ++mi)
#pragma unroll
    for (int ni = 0; ni < 4; ++ni) {
      int n = n0 + wn + ni * 16 + lm;
#pragma unroll
      for (int r = 0; r < 4; ++r) {
        int m = m0 + wm + mi * 16 + lg * 4 + r;   // D row = (lane>>4)*4 + reg
        float v = acc[mi][ni][r] + bv[ni];
        if (out_f32) Cf[(size_t)m * Nn + n] = v;
        else         Cb[(size_t)m * Nn + n] = f2bf(v);
      }
    }
}

// ---------------- fused RMSNorm + flash attention ----------------
// grid: (N/64 qblocks, NHEAD). 4 waves x 16 q-rows. KVBLK=64.
__global__ __launch_bounds__(256) void attn_kernel(
    const unsigned short* __restrict__ qb,
    const unsigned short* __restrict__ kb,
    const unsigned short* __restrict__ vb,
    const float* __restrict__ wq,
    const float* __restrict__ wk,
    unsigned short* __restrict__ ob)
{
  __shared__ __align__(16) unsigned short Kl[64 * 64];      // (kv,d) swizzled
  __shared__ __align__(16) unsigned short Vt[64 * 64];      // (d,kv) swizzled
  __shared__ __align__(16) unsigned short Pl[4][16 * 64];   // per-wave (q,kv) swizzled

  const int h   = blockIdx.y;
  const int q0  = blockIdx.x * 64;
  const int tid = threadIdx.x;
  const int wid = tid >> 6, lane = tid & 63;
  const int lm  = lane & 15, lg = lane >> 4;

  // ---- Q fragments with fused RMSNorm (weight folded) ----
  bf16x8 qf[2];
  {
    const unsigned short* qp = qb + (size_t)(q0 + wid * 16 + lm) * DM + h * HD;
    float qv[16];
    float ss = 0.f;
#pragma unroll
    for (int kt = 0; kt < 2; ++kt) {
      bf16x8 raw = *(const bf16x8*)(qp + kt * 32 + lg * 8);
#pragma unroll
      for (int j = 0; j < 8; ++j) { float f = bf2f(raw[j]); qv[kt * 8 + j] = f; ss += f * f; }
    }
    ss += __shfl_xor(ss, 16);
    ss += __shfl_xor(ss, 32);
    float inv = rsqrtf(ss * (1.f / 64.f) + 1e-5f);
#pragma unroll
    for (int kt = 0; kt < 2; ++kt)
#pragma unroll
      for (int j = 0; j < 8; ++j)
        qf[kt][j] = (short)f2bf(qv[kt * 8 + j] * wq[kt * 32 + lg * 8 + j] * inv);
  }

  f32x4 oacc[4];   // O^T accumulator: tile dt, lane holds (d = dt*16+lg*4+r, q = lm)
#pragma unroll
  for (int i = 0; i < 4; ++i) oacc[i] = f32x4{0.f, 0.f, 0.f, 0.f};
  float mrow[4] = {-1e30f, -1e30f, -1e30f, -1e30f};   // S-layout state, q-row = 4*lg+r
  float lrow[4] = {0.f, 0.f, 0.f, 0.f};

  const int kvr = tid >> 2;          // staging row 0..63
  const int c0  = (tid & 3) * 16;    // staging col quarter

  for (int kv0 = 0; kv0 < N_TOK; kv0 += 64) {
    __syncthreads();   // previous iteration's LDS reads done

    // ---- stage K with fused RMSNorm, XOR-swizzled rows ----
    {
      const unsigned short* kp = kb + (size_t)(kv0 + kvr) * DM + h * HD + c0;
      bf16x8 r0 = *(const bf16x8*)kp;
      bf16x8 r1 = *(const bf16x8*)(kp + 8);
      float f[16]; float s = 0.f;
#pragma unroll
      for (int j = 0; j < 8; ++j) { f[j] = bf2f(r0[j]); f[8 + j] = bf2f(r1[j]); }
#pragma unroll
      for (int j = 0; j < 16; ++j) s += f[j] * f[j];
      s += __shfl_xor(s, 1);
      s += __shfl_xor(s, 2);
      float inv = rsqrtf(s * (1.f / 64.f) + 1e-5f);
      bf16x8 o0, o1;
#pragma unroll
      for (int j = 0; j < 8; ++j) {
        o0[j] = (short)f2bf(f[j]     * wk[c0 + j]     * inv);
        o1[j] = (short)f2bf(f[8 + j] * wk[c0 + 8 + j] * inv);
      }
      char* base = (char*)Kl + kvr * 128;
      int swz = (kvr & 7) << 4;
      *(bf16x8*)(base + ((c0 * 2)      ^ swz)) = o0;
      *(bf16x8*)(base + ((c0 * 2 + 16) ^ swz)) = o1;
    }
    // ---- stage V transposed (d,kv), XOR-swizzled rows ----
    {
      const unsigned short* vp = vb + (size_t)(kv0 + kvr) * DM + h * HD + c0;
      bf16x8 r0 = *(const bf16x8*)vp;
      bf16x8 r1 = *(const bf16x8*)(vp + 8);
#pragma unroll
      for (int j = 0; j < 8; ++j) {
        int d0 = c0 + j, d1 = c0 + 8 + j;
        *(unsigned short*)((char*)Vt + d0 * 128 + ((kvr * 2) ^ ((d0 & 7) << 4))) = (unsigned short)r0[j];
        *(unsigned short*)((char*)Vt + d1 * 128 + ((kvr * 2) ^ ((d1 & 7) << 4))) = (unsigned short)r1[j];
      }
    }
    __syncthreads();

    // ---- S = Q K^T (16 q-rows x 64 kv per wave) ----
    f32x4 sacc[4];
#pragma unroll
    for (int ct = 0; ct < 4; ++ct) sacc[ct] = f32x4{0.f, 0.f, 0.f, 0.f};
#pragma unroll
    for (int kt = 0; kt < 2; ++kt) {
#pragma unroll
      for (int ct = 0; ct < 4; ++ct) {
        int kvrow = ct * 16 + lm;
        bf16x8 kf = *(const bf16x8*)((char*)Kl + kvrow * 128 +
                        (((kt * 64) + (lg * 16)) ^ ((kvrow & 7) << 4)));
        sacc[ct] = __builtin_amdgcn_mfma_f32_16x16x32_bf16(qf[kt], kf, sacc[ct], 0, 0, 0);
      }
    }

    // ---- online softmax (S-layout: lane holds q=4*lg+r, kv=ct*16+lm) ----
    float mt[4], scl[4], pr[4];
#pragma unroll
    for (int r = 0; r < 4; ++r) {
      float m = fmaxf(fmaxf(sacc[0][r], sacc[1][r]), fmaxf(sacc[2][r], sacc[3][r]));
      m = fmaxf(m, __shfl_xor(m, 1));
      m = fmaxf(m, __shfl_xor(m, 2));
      m = fmaxf(m, __shfl_xor(m, 4));
      m = fmaxf(m, __shfl_xor(m, 8));
      float mnew = fmaxf(mrow[r], m);
      scl[r] = __expf(mrow[r] - mnew);
      mrow[r] = mnew;
      mt[r] = mnew;
      pr[r] = 0.f;
    }
#pragma unroll
    for (int ct = 0; ct < 4; ++ct) {
#pragma unroll
      for (int r = 0; r < 4; ++r) {
        float p = __expf(sacc[ct][r] - mt[r]);
        pr[r] += p;
        int q = lg * 4 + r;
        *(unsigned short*)((char*)Pl[wid] + q * 128 +
            ((ct * 32 + lm * 2) ^ ((q & 7) << 4))) = f2bf(p);
      }
    }
#pragma unroll
    for (int r = 0; r < 4; ++r) {
      float s = pr[r];
      s += __shfl_xor(s, 1);
      s += __shfl_xor(s, 2);
      s += __shfl_xor(s, 4);
      s += __shfl_xor(s, 8);
      lrow[r] = lrow[r] * scl[r] + s;
    }
    // redistribute rescale factor to O^T layout (per-lane q = lm)
    {
      int gq = lm >> 2, rq = lm & 3;
      float t0 = __shfl(scl[0], gq << 4);
      float t1 = __shfl(scl[1], gq << 4);
      float t2 = __shfl(scl[2], gq << 4);
      float t3 = __shfl(scl[3], gq << 4);
      float sq = (rq == 0) ? t0 : ((rq == 1) ? t1 : ((rq == 2) ? t2 : t3));
#pragma unroll
      for (int dt = 0; dt < 4; ++dt) {
        oacc[dt][0] *= sq; oacc[dt][1] *= sq; oacc[dt][2] *= sq; oacc[dt][3] *= sq;
      }
    }
    // ---- O^T += V^T P^T ----
#pragma unroll
    for (int kt = 0; kt < 2; ++kt) {
      bf16x8 pf = *(const bf16x8*)((char*)Pl[wid] + lm * 128 +
                      ((kt * 64 + lg * 16) ^ ((lm & 7) << 4)));
#pragma unroll
      for (int dt = 0; dt < 4; ++dt) {
        int d = dt * 16 + lm;
        bf16x8 vf = *(const bf16x8*)((char*)Vt + d * 128 +
                        ((kt * 64 + lg * 16) ^ ((d & 7) << 4)));
        oacc[dt] = __builtin_amdgcn_mfma_f32_16x16x32_bf16(vf, pf, oacc[dt], 0, 0, 0);
      }
    }
  }

  // ---- epilogue: divide by row sum, write bf16 ----
  {
    int gq = lm >> 2, rq = lm & 3;
    float t0 = __shfl(lrow[0], gq << 4);
    float t1 = __shfl(lrow[1], gq << 4);
    float t2 = __shfl(lrow[2], gq << 4);
    float t3 = __shfl(lrow[3], gq << 4);
    float lv = (rq == 0) ? t0 : ((rq == 1) ? t1 : ((rq == 2) ? t2 : t3));
    float ilv = 1.f / lv;
    int n = q0 + wid * 16 + lm;
    unsigned short* op = ob + (size_t)n * DM + h * HD;
#pragma unroll
    for (int dt = 0; dt < 4; ++dt) {
      bf16x4 o;
      o[0] = (short)f2bf(oacc[dt][0] * ilv);
      o[1] = (short)f2bf(oacc[dt][1] * ilv);
      o[2] = (short)f2bf(oacc[dt][2] * ilv);
      o[3] = (short)f2bf(oacc[dt][3] * ilv);
      *(bf16x4*)(op + dt * 16 + lg * 4) = o;   // d = dt*16 + lg*4 + r
    }
  }
}

// ---------------- host ----------------
extern "C" void kernel_launch(void* const* d_in, const int* in_sizes, int n_in,
                              void* d_out, int out_size, void* d_ws, size_t ws_size,
                              hipStream_t stream) {
  const float* query = (const float*)d_in[0];
  const float* key   = (const float*)d_in[1];
  const float* value = (const float*)d_in[2];
  const float* Wq    = (const float*)d_in[3];
  const float* bq    = (const float*)d_in[4];
  const float* Wk    = (const float*)d_in[5];
  const float* bk    = (const float*)d_in[6];
  const float* Wv    = (const float*)d_in[7];
  const float* bv    = (const float*)d_in[8];
  const float* Wo    = (const float*)d_in[9];
  const float* bo    = (const float*)d_in[10];
  const float* qnw   = (const float*)d_in[11];
  const float* knw   = (const float*)d_in[12];

  char* ws = (char*)d_ws;
  const size_t MB = 1024 * 1024;
  unsigned short* qbf = (unsigned short*)(ws + 0 * MB);    // 8 MB each (N x D bf16)
  unsigned short* kbf = (unsigned short*)(ws + 8 * MB);
  unsigned short* vbf = (unsigned short*)(ws + 16 * MB);
  unsigned short* wqb = (unsigned short*)(ws + 24 * MB);   // 2 MB each (D x D bf16)
  unsigned short* wkb = (unsigned short*)(ws + 26 * MB);
  unsigned short* wvb = (unsigned short*)(ws + 28 * MB);
  unsigned short* wob = (unsigned short*)(ws + 30 * MB);
  unsigned short* qpj = (unsigned short*)(ws + 32 * MB);
  unsigned short* kpj = (unsigned short*)(ws + 40 * MB);
  unsigned short* vpj = (unsigned short*)(ws + 48 * MB);
  unsigned short* apj = (unsigned short*)(ws + 56 * MB);

  const int n8big = N_TOK * DM / 8;   // 524288
  const int n8w   = DM * DM / 8;      // 131072
  cvt_kernel<<<2048, 256, 0, stream>>>(query, qbf, n8big);
  cvt_kernel<<<2048, 256, 0, stream>>>(key,   kbf, n8big);
  cvt_kernel<<<2048, 256, 0, stream>>>(value, vbf, n8big);
  cvt_kernel<<<512, 256, 0, stream>>>(Wq, wqb, n8w);
  cvt_kernel<<<512, 256, 0, stream>>>(Wk, wkb, n8w);
  cvt_kernel<<<512, 256, 0, stream>>>(Wv, wvb, n8w);
  cvt_kernel<<<512, 256, 0, stream>>>(Wo, wob, n8w);

  dim3 gg(DM / 128, N_TOK / 128);
  gemm_bt<<<gg, 256, 0, stream>>>(qbf, wqb, bq, qpj, (float*)nullptr, N_TOK, DM, DM, 0);
  gemm_bt<<<gg, 256, 0, stream>>>(kbf, wkb, bk, kpj, (float*)nullptr, N_TOK, DM, DM, 0);
  gemm_bt<<<gg, 256, 0, stream>>>(vbf, wvb, bv, vpj, (float*)nullptr, N_TOK, DM, DM, 0);

  attn_kernel<<<dim3(N_TOK / 64, NHEAD), 256, 0, stream>>>(qpj, kpj, vpj, qnw, knw, apj);

  gemm_bt<<<gg, 256, 0, stream>>>(apj, wob, bo, (unsigned short*)nullptr, (float*)d_out,
                                  N_TOK, DM, DM, 1);
}

// Round 2
// 265.397 us; speedup vs baseline: 1.6742x; 1.6742x over previous
//
#include <hip/hip_runtime.h>
#include <stdint.h>
#include <stddef.h>

#define N_TOK 4096
#define DM    1024
#define NHEAD 16
#define HD    64

typedef __attribute__((ext_vector_type(8)))  short bf16x8;
typedef __attribute__((ext_vector_type(4)))  short bf16x4;
typedef __attribute__((ext_vector_type(4)))  float f32x4;
typedef __attribute__((ext_vector_type(16))) float f32x16;

static __device__ __forceinline__ float bf2f(short u) {
  union { unsigned int i; float f; } c;
  c.i = ((unsigned int)(unsigned short)u) << 16;
  return c.f;
}
static __device__ __forceinline__ unsigned short f2bf(float f) {
  union { float f; unsigned int i; } c; c.f = f;
  unsigned int x = c.i;
  return (unsigned short)((x + 0x7fffu + ((x >> 16) & 1u)) >> 16);
}
static __device__ __forceinline__ unsigned int cvtpk(float lo, float hi) {
  unsigned int d;
  asm("v_cvt_pk_bf16_f32 %0, %1, %2" : "=v"(d) : "v"(lo), "v"(hi));
  return d;
}
static __device__ __forceinline__ void plswap(unsigned int& a, unsigned int& b) {
  asm("v_permlane32_swap_b32 %0, %1" : "+v"(a), "+v"(b));
}
// async global->LDS, 16B/lane; LDS dest wave-uniform base (HW adds lane*16)
static __device__ __forceinline__ void gload16(const void* g, void* l) {
  __builtin_amdgcn_global_load_lds(
      (const __attribute__((address_space(1))) unsigned int*)g,
      (__attribute__((address_space(3))) unsigned int*)l, 16, 0, 0);
}

// ---------------- fp32 -> bf16 conversion ----------------
__global__ void cvt_kernel(const float* __restrict__ src,
                           unsigned short* __restrict__ dst, int n8) {
  int i = blockIdx.x * blockDim.x + threadIdx.x;
  int stride = gridDim.x * blockDim.x;
  for (; i < n8; i += stride) {
    const f32x4* s = (const f32x4*)(src + (size_t)i * 8);
    f32x4 a = s[0], b = s[1];
    bf16x8 o;
    o[0] = (short)f2bf(a[0]); o[1] = (short)f2bf(a[1]);
    o[2] = (short)f2bf(a[2]); o[3] = (short)f2bf(a[3]);
    o[4] = (short)f2bf(b[0]); o[5] = (short)f2bf(b[1]);
    o[6] = (short)f2bf(b[2]); o[7] = (short)f2bf(b[3]);
    *(bf16x8*)(dst + (size_t)i * 8) = o;
  }
}

// ---------------- C = A @ W^T + bias (128x128 tile m97-style) ----------------
// modes: 0 = bf16 row-major out; 1 = f32 row-major out;
//        2 = per-head RMSNorm -> Kn[h][n][64] bf16;  3 = transpose -> Vt[h][d][n] bf16
__global__ __launch_bounds__(256) void gemm_bt(
    const unsigned short* __restrict__ A,
    const unsigned short* __restrict__ W,
    const float* __restrict__ bias,
    unsigned short* __restrict__ Cb,
    float* __restrict__ Cf,
    const float* __restrict__ nw,
    int M, int Nn, int K, int mode)
{
  __shared__ __align__(16) unsigned short At[128 * 32];
  __shared__ __align__(16) unsigned short Wt[128 * 32];
  const int tid  = threadIdx.x;
  const int wid  = tid >> 6, lane = tid & 63;
  const int lm   = lane & 15, lg = lane >> 4;
  const int m0   = blockIdx.y * 128, n0 = blockIdx.x * 128;
  const int wm   = (wid >> 1) * 64,  wn = (wid & 1) * 64;

  f32x4 acc[4][4];
#pragma unroll
  for (int i = 0; i < 4; ++i)
#pragma unroll
    for (int j = 0; j < 4; ++j) acc[i][j] = f32x4{0.f, 0.f, 0.f, 0.f};

  for (int k0 = 0; k0 < K; k0 += 32) {
    __syncthreads();
#pragma unroll
    for (int i = 0; i < 2; ++i) {
      int ca = wid * 64 + lane + i * 256;
      gload16(A + (size_t)(m0 + (ca >> 2)) * K + (k0 + (ca & 3) * 8),
              (char*)At + (size_t)(wid * 64 + i * 256) * 16);
      gload16(W + (size_t)(n0 + (ca >> 2)) * K + (k0 + (ca & 3) * 8),
              (char*)Wt + (size_t)(wid * 64 + i * 256) * 16);
    }
    __syncthreads();

    bf16x8 af[4], bfr[4];
#pragma unroll
    for (int mi = 0; mi < 4; ++mi)
      af[mi] = *(const bf16x8*)&At[(wm + mi * 16 + lm) * 32 + lg * 8];
#pragma unroll
    for (int ni = 0; ni < 4; ++ni)
      bfr[ni] = *(const bf16x8*)&Wt[(wn + ni * 16 + lm) * 32 + lg * 8];
#pragma unroll
    for (int mi = 0; mi < 4; ++mi)
#pragma unroll
      for (int ni = 0; ni < 4; ++ni)
        acc[mi][ni] = __builtin_amdgcn_mfma_f32_16x16x32_bf16(
            af[mi], bfr[ni], acc[mi][ni], 0, 0, 0);
  }

  float bv[4];
#pragma unroll
  for (int ni = 0; ni < 4; ++ni) bv[ni] = bias[n0 + wn + ni * 16 + lm];

  if (mode <= 1) {
#pragma unroll
    for (int mi = 0; mi < 4; ++mi)
#pragma unroll
      for (int ni = 0; ni < 4; ++ni) {
        int n = n0 + wn + ni * 16 + lm;
#pragma unroll
        for (int r = 0; r < 4; ++r) {
          int m = m0 + wm + mi * 16 + lg * 4 + r;
          float v = acc[mi][ni][r] + bv[ni];
          if (mode == 1) Cf[(size_t)m * Nn + n] = v;
          else           Cb[(size_t)m * Nn + n] = f2bf(v);
        }
      }
  } else if (mode == 2) {
    // K path: rows are tokens, this wave's 64 cols = one full head
    const int h = (n0 + wn) >> 6;
    float w_[4];
#pragma unroll
    for (int ni = 0; ni < 4; ++ni) w_[ni] = nw[ni * 16 + lm];
#pragma unroll
    for (int mi = 0; mi < 4; ++mi) {
      float t[4][4], ssq[4];
#pragma unroll
      for (int ni = 0; ni < 4; ++ni)
#pragma unroll
        for (int r = 0; r < 4; ++r) t[ni][r] = acc[mi][ni][r] + bv[ni];
#pragma unroll
      for (int r = 0; r < 4; ++r)
        ssq[r] = t[0][r]*t[0][r] + t[1][r]*t[1][r] + t[2][r]*t[2][r] + t[3][r]*t[3][r];
#pragma unroll
      for (int r = 0; r < 4; ++r) {
        ssq[r] += __shfl_xor(ssq[r], 1);
        ssq[r] += __shfl_xor(ssq[r], 2);
        ssq[r] += __shfl_xor(ssq[r], 4);
        ssq[r] += __shfl_xor(ssq[r], 8);
      }
#pragma unroll
      for (int r = 0; r < 4; ++r) {
        float iv = rsqrtf(ssq[r] * (1.f / 64.f) + 1e-5f);
        int n_ = m0 + wm + mi * 16 + lg * 4 + r;   // token index
#pragma unroll
        for (int ni = 0; ni < 4; ++ni) {
          int d = ni * 16 + lm;
          Cb[(size_t)h * (N_TOK * HD) + (size_t)n_ * HD + d] = f2bf(t[ni][r] * w_[ni] * iv);
        }
      }
    }
  } else {
    // V path: transpose to Vt[h][d][n]; r-consecutive tokens pack into 8B stores
    const int h = (n0 + wn) >> 6;
#pragma unroll
    for (int mi = 0; mi < 4; ++mi)
#pragma unroll
      for (int ni = 0; ni < 4; ++ni) {
        int d  = ni * 16 + lm;
        int nb = m0 + wm + mi * 16 + lg * 4;
        bf16x4 o;
#pragma unroll
        for (int r = 0; r < 4; ++r) o[r] = (short)f2bf(acc[mi][ni][r] + bv[ni]);
        *(bf16x4*)&Cb[(size_t)h * (HD * N_TOK) + (size_t)d * N_TOK + nb] = o;
      }
  }
}

// ---------------- fused RMSNorm(Q) + flash attention, swapped-QK 32x32 ----------------
// grid: (N/128, NHEAD), 4 waves x 32 q-rows. KVBLK=64. Static softmax max = 40.
#define CSUB 57.70780163555853f   // 40 * log2(e)
__global__ __launch_bounds__(256) void attn_kernel(
    const unsigned short* __restrict__ qb,   // (n, 1024) bf16, plain
    const unsigned short* __restrict__ kn,   // Kn[h][kv][64] bf16, normalized
    const unsigned short* __restrict__ vt,   // Vt[h][d][kv] bf16
    const float* __restrict__ wq,            // q_norm_w[64]
    unsigned short* __restrict__ ob)         // (n, 1024) bf16
{
  __shared__ __align__(16) unsigned short Kl[64 * 64];   // [kv][d] swizzled
  __shared__ __align__(16) unsigned short Vl[64 * 64];   // [d][kv] swizzled

  const int h    = blockIdx.y;
  const int tid  = threadIdx.x;
  const int wid  = tid >> 6, lane = tid & 63;
  const int l31  = lane & 31, hi = lane >> 5;
  const int sl   = l31 & 7;
  const int qbase = blockIdx.x * 128 + wid * 32;

  // ---- Q fragments, RMSNorm fused, scaled by log2(e) ----
  bf16x8 qf[4];
  {
    const unsigned short* qp = qb + (size_t)(qbase + l31) * DM + h * HD + hi * 8;
    float qv[32]; float ss = 0.f;
#pragma unroll
    for (int s = 0; s < 4; ++s) {
      bf16x8 raw = *(const bf16x8*)(qp + s * 16);
#pragma unroll
      for (int j = 0; j < 8; ++j) { float f = bf2f(raw[j]); qv[s*8+j] = f; ss += f*f; }
    }
    ss += __shfl_xor(ss, 32);
    float inv = rsqrtf(ss * (1.f / 64.f) + 1e-5f) * 1.44269504f;
#pragma unroll
    for (int s = 0; s < 4; ++s)
#pragma unroll
      for (int j = 0; j < 8; ++j)
        qf[s][j] = (short)f2bf(qv[s*8+j] * wq[s*16 + hi*8 + j] * inv);
  }

  // ---- LDS read offsets: slot[x] = ((2x+hi)^sl)<<4, base = l31*128 ----
  int slot[4];
#pragma unroll
  for (int x = 0; x < 4; ++x) slot[x] = (((2*x + hi) ^ sl) << 4);
  const char* KlB = (const char*)Kl + l31 * 128;
  const char* VlB = (const char*)Vl + l31 * 128;

  // ---- staging sources (pre-swizzled global addresses), 4 chunks/wave ----
  const char* gsrc[4];
  char*       ldst[4];
  long        gstep[4];
  {
    const char* knb = (const char*)kn + (size_t)h * (N_TOK * HD * 2);
    const char* vtb = (const char*)vt + (size_t)h * (HD * N_TOK * 2);
#pragma unroll
    for (int i = 0; i < 4; ++i) {
      int chunk = wid * 4 + i;           // 0..7 K, 8..15 V
      int off   = (chunk & 7) * 1024 + lane * 16;
      int row   = off >> 7;              // 0..63
      int scol  = (off & 127) ^ ((row & 7) << 4);
      if (chunk < 8) {
        gsrc[i]  = knb + (size_t)row * 128 + scol;   // + kv0*128 per tile
        gstep[i] = 64 * 128;
        ldst[i]  = (char*)Kl + (chunk & 7) * 1024;
      } else {
        gsrc[i]  = vtb + (size_t)row * (N_TOK * 2) + scol;  // + kv0*2 per tile
        gstep[i] = 64 * 2;
        ldst[i]  = (char*)Vl + (chunk & 7) * 1024;
      }
    }
  }

  f32x16 oacc[2];
#pragma unroll
  for (int dt = 0; dt < 2; ++dt)
#pragma unroll
    for (int r = 0; r < 16; ++r) oacc[dt][r] = 0.f;
  float ls = 0.f;

  for (int it = 0; it < N_TOK / 64; ++it) {
    __syncthreads();
#pragma unroll
    for (int i = 0; i < 4; ++i) {
      gload16(gsrc[i], ldst[i]);
      gsrc[i] += gstep[i];
    }
    __syncthreads();

#pragma unroll
    for (int kt = 0; kt < 2; ++kt) {
      // S^T = K Q^T over 32 kv x 32 q
      f32x16 sc = {0,0,0,0,0,0,0,0,0,0,0,0,0,0,0,0};
#pragma unroll
      for (int s = 0; s < 4; ++s) {
        bf16x8 kf = *(const bf16x8*)(KlB + kt * 4096 + slot[s]);
        sc = __builtin_amdgcn_mfma_f32_32x32x16_bf16(kf, qf[s], sc, 0, 0, 0);
      }
      // softmax vs static max: P = 2^(s' - CSUB), s' = log2e * s
      float e[16];
#pragma unroll
      for (int r = 0; r < 16; ++r) { e[r] = exp2f(sc[r] - CSUB); ls += e[r]; }
      // pack to bf16 dwords W[b] = {(c0,c1),(c2,c3)}, b = r>>2
      unsigned int wpk[4][2];
#pragma unroll
      for (int b = 0; b < 4; ++b) {
        wpk[b][0] = cvtpk(e[4*b+0], e[4*b+1]);
        wpk[b][1] = cvtpk(e[4*b+2], e[4*b+3]);
      }
      // permlane32_swap: even-b pack (op0) serves hi=0 lanes, odd-b (op1) hi=1 lanes
#pragma unroll
      for (int pr = 0; pr < 2; ++pr) {
        unsigned int x0 = wpk[2*pr][0], x1 = wpk[2*pr][1];
        unsigned int y0 = wpk[2*pr+1][0], y1 = wpk[2*pr+1][1];
        plswap(x0, y0);   // x := lo-sourced word, y := hi-sourced word
        plswap(x1, y1);
        union { unsigned int u[4]; bf16x8 v; } pa;
        pa.u[0] = x0; pa.u[1] = x1; pa.u[2] = y0; pa.u[3] = y1;
        int ks = kt * 2 + pr;
#pragma unroll
        for (int dt = 0; dt < 2; ++dt) {
          bf16x8 vf = *(const bf16x8*)(VlB + dt * 4096 + slot[ks]);
          oacc[dt] = __builtin_amdgcn_mfma_f32_32x32x16_bf16(pa.v, vf, oacc[dt], 0, 0, 0);
        }
      }
    }
  }

  // ---- epilogue: O /= rowsum, write bf16 ----
  ls += __shfl_xor(ls, 32);
  float il = 1.f / ls;
#pragma unroll
  for (int r = 0; r < 16; ++r) {
    int q = (r & 3) + 8 * (r >> 2) + 4 * hi;
    float ilr = __int_as_float(
        __builtin_amdgcn_ds_bpermute(q << 2, __float_as_int(il)));
    unsigned short* op = ob + (size_t)(qbase + q) * DM + h * HD + l31;
    op[0]  = f2bf(oacc[0][r] * ilr);
    op[32] = f2bf(oacc[1][r] * ilr);
  }
}

// ---------------- host ----------------
extern "C" void kernel_launch(void* const* d_in, const int* in_sizes, int n_in,
                              void* d_out, int out_size, void* d_ws, size_t ws_size,
                              hipStream_t stream) {
  const float* query = (const float*)d_in[0];
  const float* key   = (const float*)d_in[1];
  const float* value = (const float*)d_in[2];
  const float* Wq    = (const float*)d_in[3];
  const float* bq    = (const float*)d_in[4];
  const float* Wk    = (const float*)d_in[5];
  const float* bk    = (const float*)d_in[6];
  const float* Wv    = (const float*)d_in[7];
  const float* bv    = (const float*)d_in[8];
  const float* Wo    = (const float*)d_in[9];
  const float* bo    = (const float*)d_in[10];
  const float* qnw   = (const float*)d_in[11];
  const float* knw   = (const float*)d_in[12];

  char* ws = (char*)d_ws;
  const size_t MB = 1024 * 1024;
  unsigned short* qbf = (unsigned short*)(ws + 0 * MB);
  unsigned short* kbf = (unsigned short*)(ws + 8 * MB);
  unsigned short* vbf = (unsigned short*)(ws + 16 * MB);
  unsigned short* wqb = (unsigned short*)(ws + 24 * MB);
  unsigned short* wkb = (unsigned short*)(ws + 26 * MB);
  unsigned short* wvb = (unsigned short*)(ws + 28 * MB);
  unsigned short* wob = (unsigned short*)(ws + 30 * MB);
  unsigned short* qpj = (unsigned short*)(ws + 32 * MB);   // Q projected (n,1024)
  unsigned short* Kn  = (unsigned short*)(ws + 40 * MB);   // [h][kv][64] normalized
  unsigned short* Vt  = (unsigned short*)(ws + 48 * MB);   // [h][d][kv]
  unsigned short* apj = (unsigned short*)(ws + 56 * MB);   // attn out (n,1024)

  const int n8big = N_TOK * DM / 8;
  const int n8w   = DM * DM / 8;
  cvt_kernel<<<2048, 256, 0, stream>>>(query, qbf, n8big);
  cvt_kernel<<<2048, 256, 0, stream>>>(key,   kbf, n8big);
  cvt_kernel<<<2048, 256, 0, stream>>>(value, vbf, n8big);
  cvt_kernel<<<512, 256, 0, stream>>>(Wq, wqb, n8w);
  cvt_kernel<<<512, 256, 0, stream>>>(Wk, wkb, n8w);
  cvt_kernel<<<512, 256, 0, stream>>>(Wv, wvb, n8w);
  cvt_kernel<<<512, 256, 0, stream>>>(Wo, wob, n8w);

  dim3 gg(DM / 128, N_TOK / 128);
  gemm_bt<<<gg, 256, 0, stream>>>(qbf, wqb, bq, qpj, nullptr, nullptr, N_TOK, DM, DM, 0);
  gemm_bt<<<gg, 256, 0, stream>>>(kbf, wkb, bk, Kn,  nullptr, knw,     N_TOK, DM, DM, 2);
  gemm_bt<<<gg, 256, 0, stream>>>(vbf, wvb, bv, Vt,  nullptr, nullptr, N_TOK, DM, DM, 3);

  attn_kernel<<<dim3(N_TOK / 128, NHEAD), 256, 0, stream>>>(qpj, Kn, Vt, qnw, apj);

  gemm_bt<<<gg, 256, 0, stream>>>(apj, wob, bo, nullptr, (float*)d_out, nullptr,
                                  N_TOK, DM, DM, 1);
}

// Round 3
// 202.531 us; speedup vs baseline: 2.1939x; 1.3104x over previous
//
#include <hip/hip_runtime.h>
#include <stdint.h>
#include <stddef.h>

#define N_TOK 4096
#define DM    1024
#define NHEAD 16
#define HD    64

typedef __attribute__((ext_vector_type(8)))  short bf16x8;
typedef __attribute__((ext_vector_type(4)))  short bf16x4;
typedef __attribute__((ext_vector_type(4)))  float f32x4;
typedef __attribute__((ext_vector_type(16))) float f32x16;

static __device__ __forceinline__ float bf2f(short u) {
  union { unsigned int i; float f; } c;
  c.i = ((unsigned int)(unsigned short)u) << 16;
  return c.f;
}
static __device__ __forceinline__ unsigned short f2bf(float f) {
  union { float f; unsigned int i; } c; c.f = f;
  unsigned int x = c.i;
  return (unsigned short)((x + 0x7fffu + ((x >> 16) & 1u)) >> 16);
}
static __device__ __forceinline__ unsigned int cvtpk(float lo, float hi) {
  unsigned int d;
  asm("v_cvt_pk_bf16_f32 %0, %1, %2" : "=v"(d) : "v"(lo), "v"(hi));
  return d;
}
static __device__ __forceinline__ void plswap(unsigned int& a, unsigned int& b) {
  asm("v_permlane32_swap_b32 %0, %1" : "+v"(a), "+v"(b));
}
#if __has_builtin(__builtin_amdgcn_exp2f)
#define EXP2(x) __builtin_amdgcn_exp2f(x)
#else
#define EXP2(x) exp2f(x)
#endif
// async global->LDS, 16B/lane; LDS dest wave-uniform base (HW adds lane*16)
static __device__ __forceinline__ void gload16(const void* g, void* l) {
  __builtin_amdgcn_global_load_lds(
      (const __attribute__((address_space(1))) unsigned int*)g,
      (__attribute__((address_space(3))) unsigned int*)l, 16, 0, 0);
}

// ---------------- fused fp32 -> bf16 conversion (all 7 tensors, 1 launch) ----------------
struct Cvt7 { const float* s[7]; unsigned short* d[7]; };
// units of 8 elems: segs 0..2 = 524288 each (q,k,v), 3..6 = 131072 each (weights)
__global__ void cvt_all(Cvt7 a) {
  int u0 = blockIdx.x << 10;              // 1024 units per block, uniform segment
  int seg, off;
  if (u0 < 1572864) { seg = u0 >> 19; off = u0 & 524287; }
  else { int j = u0 - 1572864; seg = 3 + (j >> 17); off = j & 131071; }
  const float* s = a.s[seg];
  unsigned short* dd = a.d[seg];
  int t = off + threadIdx.x;
#pragma unroll
  for (int j = 0; j < 4; ++j, t += 256) {
    const f32x4* sp = (const f32x4*)(s + (size_t)t * 8);
    f32x4 x = sp[0], y = sp[1];
    bf16x8 o;
    o[0] = (short)f2bf(x[0]); o[1] = (short)f2bf(x[1]);
    o[2] = (short)f2bf(x[2]); o[3] = (short)f2bf(x[3]);
    o[4] = (short)f2bf(y[0]); o[5] = (short)f2bf(y[1]);
    o[6] = (short)f2bf(y[2]); o[7] = (short)f2bf(y[3]);
    *(bf16x8*)(dd + (size_t)t * 8) = o;
  }
}

// ---------------- C = A @ W^T + bias  (64M x 128N tile, double-buffered) ----------------
// modes: 0 = bf16 row-major out; 1 = f32 row-major out;
//        2 = per-head RMSNorm -> Kn[h][n][64] bf16;  3 = transpose -> Vt[h][d][n] bf16
__global__ __launch_bounds__(256) void gemm_bt(
    const unsigned short* __restrict__ A,
    const unsigned short* __restrict__ W,
    const float* __restrict__ bias,
    unsigned short* __restrict__ Cb,
    float* __restrict__ Cf,
    const float* __restrict__ nw,
    int M, int Nn, int K, int mode)
{
  __shared__ __align__(16) unsigned short At[2][64 * 32];    // 4KB per buf
  __shared__ __align__(16) unsigned short Wt[2][128 * 32];   // 8KB per buf
  const int tid  = threadIdx.x;
  const int wid  = tid >> 6, lane = tid & 63;
  const int lm   = lane & 15, lg = lane >> 4;
  const int m0   = blockIdx.y * 64, n0 = blockIdx.x * 128;
  const int wm   = (wid >> 1) * 32,  wn = (wid & 1) * 64;

  f32x4 acc[2][4];
#pragma unroll
  for (int i = 0; i < 2; ++i)
#pragma unroll
    for (int j = 0; j < 4; ++j) acc[i][j] = f32x4{0.f, 0.f, 0.f, 0.f};

  auto stage = [&](int b, int k0) {
#pragma unroll
    for (int i = 0; i < 3; ++i) {
      int c = wid * 3 + i;                 // 0..3 = A chunks, 4..11 = W chunks
      if (c < 4)
        gload16(A + (size_t)(m0 + c * 16 + (lane >> 2)) * K + k0 + (lane & 3) * 8,
                (char*)At + b * 4096 + c * 1024);
      else
        gload16(W + (size_t)(n0 + (c - 4) * 16 + (lane >> 2)) * K + k0 + (lane & 3) * 8,
                (char*)Wt + b * 8192 + (c - 4) * 1024);
    }
  };

  const int nk = K >> 5;
  stage(0, 0);
  __syncthreads();
  for (int kt = 0; kt < nk; ++kt) {
    const int cur = kt & 1;
    if (kt + 1 < nk) stage(cur ^ 1, (kt + 1) << 5);

    bf16x8 af[2], bfr[4];
#pragma unroll
    for (int mi = 0; mi < 2; ++mi)
      af[mi] = *(const bf16x8*)&At[cur][(wm + mi * 16 + lm) * 32 + lg * 8];
#pragma unroll
    for (int ni = 0; ni < 4; ++ni)
      bfr[ni] = *(const bf16x8*)&Wt[cur][(wn + ni * 16 + lm) * 32 + lg * 8];
#pragma unroll
    for (int mi = 0; mi < 2; ++mi)
#pragma unroll
      for (int ni = 0; ni < 4; ++ni)
        acc[mi][ni] = __builtin_amdgcn_mfma_f32_16x16x32_bf16(
            af[mi], bfr[ni], acc[mi][ni], 0, 0, 0);
    __syncthreads();
  }

  float bv[4];
#pragma unroll
  for (int ni = 0; ni < 4; ++ni) bv[ni] = bias[n0 + wn + ni * 16 + lm];

  if (mode <= 1) {
#pragma unroll
    for (int mi = 0; mi < 2; ++mi)
#pragma unroll
      for (int ni = 0; ni < 4; ++ni) {
        int n = n0 + wn + ni * 16 + lm;
#pragma unroll
        for (int r = 0; r < 4; ++r) {
          int m = m0 + wm + mi * 16 + lg * 4 + r;
          float v = acc[mi][ni][r] + bv[ni];
          if (mode == 1) Cf[(size_t)m * Nn + n] = v;
          else           Cb[(size_t)m * Nn + n] = f2bf(v);
        }
      }
  } else if (mode == 2) {
    // K path: wave's 64 cols = one full head; fused RMSNorm over d
    const int h = (n0 + wn) >> 6;
    float w_[4];
#pragma unroll
    for (int ni = 0; ni < 4; ++ni) w_[ni] = nw[ni * 16 + lm];
#pragma unroll
    for (int mi = 0; mi < 2; ++mi) {
      float t[4][4], ssq[4];
#pragma unroll
      for (int ni = 0; ni < 4; ++ni)
#pragma unroll
        for (int r = 0; r < 4; ++r) t[ni][r] = acc[mi][ni][r] + bv[ni];
#pragma unroll
      for (int r = 0; r < 4; ++r)
        ssq[r] = t[0][r]*t[0][r] + t[1][r]*t[1][r] + t[2][r]*t[2][r] + t[3][r]*t[3][r];
#pragma unroll
      for (int r = 0; r < 4; ++r) {
        ssq[r] += __shfl_xor(ssq[r], 1);
        ssq[r] += __shfl_xor(ssq[r], 2);
        ssq[r] += __shfl_xor(ssq[r], 4);
        ssq[r] += __shfl_xor(ssq[r], 8);
      }
#pragma unroll
      for (int r = 0; r < 4; ++r) {
        float iv = rsqrtf(ssq[r] * (1.f / 64.f) + 1e-5f);
        int n_ = m0 + wm + mi * 16 + lg * 4 + r;
#pragma unroll
        for (int ni = 0; ni < 4; ++ni) {
          int d = ni * 16 + lm;
          Cb[(size_t)h * (N_TOK * HD) + (size_t)n_ * HD + d] = f2bf(t[ni][r] * w_[ni] * iv);
        }
      }
    }
  } else {
    // V path: transpose to Vt[h][d][n]
    const int h = (n0 + wn) >> 6;
#pragma unroll
    for (int mi = 0; mi < 2; ++mi)
#pragma unroll
      for (int ni = 0; ni < 4; ++ni) {
        int d  = ni * 16 + lm;
        int nb = m0 + wm + mi * 16 + lg * 4;
        bf16x4 o;
#pragma unroll
        for (int r = 0; r < 4; ++r) o[r] = (short)f2bf(acc[mi][ni][r] + bv[ni]);
        *(bf16x4*)&Cb[(size_t)h * (HD * N_TOK) + (size_t)d * N_TOK + nb] = o;
      }
  }
}

// ---------------- fused RMSNorm(Q) + flash attention, swapped-QK 32x32, dbuf ----------------
#define CSUB 57.70780163555853f   // 40 * log2(e); |logit| <= 64 so exp2 arg <= 34.6
__global__ __launch_bounds__(256) void attn_kernel(
    const unsigned short* __restrict__ qb,   // (n, 1024) bf16
    const unsigned short* __restrict__ kn,   // Kn[h][kv][64] bf16, normalized
    const unsigned short* __restrict__ vt,   // Vt[h][d][kv] bf16
    const float* __restrict__ wq,            // q_norm_w[64]
    unsigned short* __restrict__ ob)         // (n, 1024) bf16
{
  __shared__ __align__(16) unsigned short Kl[2][64 * 64];   // 8KB per buf
  __shared__ __align__(16) unsigned short Vl[2][64 * 64];

  // XCD-aware decode: XCD x (= wgid%8 under round-robin) owns heads {2x, 2x+1}
  const int wg  = blockIdx.x;          // 0..511
  const int o_  = wg >> 3;
  const int h   = (wg & 7) * 2 + (o_ >> 5);
  const int tid = threadIdx.x;
  const int wid = tid >> 6, lane = tid & 63;
  const int l31 = lane & 31, hi = lane >> 5;
  const int sl  = l31 & 7;
  const int qbase = (o_ & 31) * 128 + wid * 32;

  // ---- Q fragments, RMSNorm fused, scaled by log2(e) ----
  bf16x8 qf[4];
  {
    const unsigned short* qp = qb + (size_t)(qbase + l31) * DM + h * HD + hi * 8;
    float qv[32]; float ss = 0.f;
#pragma unroll
    for (int s = 0; s < 4; ++s) {
      bf16x8 raw = *(const bf16x8*)(qp + s * 16);
#pragma unroll
      for (int j = 0; j < 8; ++j) { float f = bf2f(raw[j]); qv[s*8+j] = f; ss += f*f; }
    }
    ss += __shfl_xor(ss, 32);
    float inv = rsqrtf(ss * (1.f / 64.f) + 1e-5f) * 1.44269504f;
#pragma unroll
    for (int s = 0; s < 4; ++s)
#pragma unroll
      for (int j = 0; j < 8; ++j)
        qf[s][j] = (short)f2bf(qv[s*8+j] * wq[s*16 + hi*8 + j] * inv);
  }

  int slot[4];
#pragma unroll
  for (int x = 0; x < 4; ++x) slot[x] = (((2*x + hi) ^ sl) << 4);
  const char* KlB = (const char*)Kl + l31 * 128;
  const char* VlB = (const char*)Vl + l31 * 128;

  // staging sources (pre-swizzled global addresses), 4 chunks/wave
  const char* gsrc[4];
  char*       ldst[4];
  long        gstep[4];
  {
    const char* knb = (const char*)kn + (size_t)h * (N_TOK * HD * 2);
    const char* vtb = (const char*)vt + (size_t)h * (HD * N_TOK * 2);
#pragma unroll
    for (int i = 0; i < 4; ++i) {
      int chunk = wid * 4 + i;           // 0..7 K, 8..15 V
      int off   = (chunk & 7) * 1024 + lane * 16;
      int row   = off >> 7;
      int scol  = (off & 127) ^ ((row & 7) << 4);
      if (chunk < 8) {
        gsrc[i]  = knb + (size_t)row * 128 + scol;
        gstep[i] = 64 * 128;
        ldst[i]  = (char*)Kl + (chunk & 7) * 1024;
      } else {
        gsrc[i]  = vtb + (size_t)row * (N_TOK * 2) + scol;
        gstep[i] = 64 * 2;
        ldst[i]  = (char*)Vl + (chunk & 7) * 1024;
      }
    }
  }

  f32x16 oacc[2];
#pragma unroll
  for (int dt = 0; dt < 2; ++dt)
#pragma unroll
    for (int r = 0; r < 16; ++r) oacc[dt][r] = 0.f;
  float lsp[4] = {0.f, 0.f, 0.f, 0.f};

  // prologue: stage tile 0 into buf 0
#pragma unroll
  for (int i = 0; i < 4; ++i) { gload16(gsrc[i], ldst[i]); gsrc[i] += gstep[i]; }
  __syncthreads();

  const int NT = N_TOK / 64;
  for (int it = 0; it < NT; ++it) {
    const int cur = it & 1;
    if (it + 1 < NT) {
      const int nb = cur ^ 1;
#pragma unroll
      for (int i = 0; i < 4; ++i) {
        gload16(gsrc[i], ldst[i] + (nb << 13));
        gsrc[i] += gstep[i];
      }
    }
    const char* KB = KlB + (cur << 13);
    const char* VB = VlB + (cur << 13);

#pragma unroll
    for (int kt = 0; kt < 2; ++kt) {
      // S^T = K Q^T over 32 kv x 32 q; acc pre-seeded with -CSUB
      f32x16 sc;
#pragma unroll
      for (int r = 0; r < 16; ++r) sc[r] = -CSUB;
      __builtin_amdgcn_s_setprio(1);
#pragma unroll
      for (int s = 0; s < 4; ++s) {
        bf16x8 kf = *(const bf16x8*)(KB + kt * 4096 + slot[s]);
        sc = __builtin_amdgcn_mfma_f32_32x32x16_bf16(kf, qf[s], sc, 0, 0, 0);
      }
      __builtin_amdgcn_s_setprio(0);
      float e[16];
#pragma unroll
      for (int r = 0; r < 16; ++r) { e[r] = EXP2(sc[r]); lsp[r & 3] += e[r]; }
      unsigned int wpk[4][2];
#pragma unroll
      for (int b = 0; b < 4; ++b) {
        wpk[b][0] = cvtpk(e[4*b+0], e[4*b+1]);
        wpk[b][1] = cvtpk(e[4*b+2], e[4*b+3]);
      }
#pragma unroll
      for (int pr = 0; pr < 2; ++pr) {
        unsigned int x0 = wpk[2*pr][0], x1 = wpk[2*pr][1];
        unsigned int y0 = wpk[2*pr+1][0], y1 = wpk[2*pr+1][1];
        plswap(x0, y0);
        plswap(x1, y1);
        union { unsigned int u[4]; bf16x8 v; } pa;
        pa.u[0] = x0; pa.u[1] = x1; pa.u[2] = y0; pa.u[3] = y1;
        int ks = kt * 2 + pr;
        __builtin_amdgcn_s_setprio(1);
#pragma unroll
        for (int dt = 0; dt < 2; ++dt) {
          bf16x8 vf = *(const bf16x8*)(VB + dt * 4096 + slot[ks]);
          oacc[dt] = __builtin_amdgcn_mfma_f32_32x32x16_bf16(pa.v, vf, oacc[dt], 0, 0, 0);
        }
        __builtin_amdgcn_s_setprio(0);
      }
    }
    __syncthreads();
  }

  // ---- epilogue: O /= rowsum, write bf16 ----
  float ls = (lsp[0] + lsp[1]) + (lsp[2] + lsp[3]);
  ls += __shfl_xor(ls, 32);
  float il = 1.f / ls;
#pragma unroll
  for (int r = 0; r < 16; ++r) {
    int q = (r & 3) + 8 * (r >> 2) + 4 * hi;
    float ilr = __int_as_float(
        __builtin_amdgcn_ds_bpermute(q << 2, __float_as_int(il)));
    unsigned short* op = ob + (size_t)(qbase + q) * DM + h * HD + l31;
    op[0]  = f2bf(oacc[0][r] * ilr);
    op[32] = f2bf(oacc[1][r] * ilr);
  }
}

// ---------------- host ----------------
extern "C" void kernel_launch(void* const* d_in, const int* in_sizes, int n_in,
                              void* d_out, int out_size, void* d_ws, size_t ws_size,
                              hipStream_t stream) {
  const float* query = (const float*)d_in[0];
  const float* key   = (const float*)d_in[1];
  const float* value = (const float*)d_in[2];
  const float* Wq    = (const float*)d_in[3];
  const float* bq    = (const float*)d_in[4];
  const float* Wk    = (const float*)d_in[5];
  const float* bk    = (const float*)d_in[6];
  const float* Wv    = (const float*)d_in[7];
  const float* bv    = (const float*)d_in[8];
  const float* Wo    = (const float*)d_in[9];
  const float* bo    = (const float*)d_in[10];
  const float* qnw   = (const float*)d_in[11];
  const float* knw   = (const float*)d_in[12];

  char* ws = (char*)d_ws;
  const size_t MB = 1024 * 1024;
  unsigned short* qbf = (unsigned short*)(ws + 0 * MB);
  unsigned short* kbf = (unsigned short*)(ws + 8 * MB);
  unsigned short* vbf = (unsigned short*)(ws + 16 * MB);
  unsigned short* wqb = (unsigned short*)(ws + 24 * MB);
  unsigned short* wkb = (unsigned short*)(ws + 26 * MB);
  unsigned short* wvb = (unsigned short*)(ws + 28 * MB);
  unsigned short* wob = (unsigned short*)(ws + 30 * MB);
  unsigned short* qpj = (unsigned short*)(ws + 32 * MB);   // Q projected (n,1024)
  unsigned short* Kn  = (unsigned short*)(ws + 40 * MB);   // [h][kv][64] normalized
  unsigned short* Vt  = (unsigned short*)(ws + 48 * MB);   // [h][d][kv]
  unsigned short* apj = (unsigned short*)(ws + 56 * MB);   // attn out (n,1024)

  Cvt7 ca;
  ca.s[0] = query; ca.d[0] = qbf;
  ca.s[1] = key;   ca.d[1] = kbf;
  ca.s[2] = value; ca.d[2] = vbf;
  ca.s[3] = Wq;    ca.d[3] = wqb;
  ca.s[4] = Wk;    ca.d[4] = wkb;
  ca.s[5] = Wv;    ca.d[5] = wvb;
  ca.s[6] = Wo;    ca.d[6] = wob;
  cvt_all<<<2048, 256, 0, stream>>>(ca);

  dim3 gg(DM / 128, N_TOK / 64);
  gemm_bt<<<gg, 256, 0, stream>>>(qbf, wqb, bq, qpj, nullptr, nullptr, N_TOK, DM, DM, 0);
  gemm_bt<<<gg, 256, 0, stream>>>(kbf, wkb, bk, Kn,  nullptr, knw,     N_TOK, DM, DM, 2);
  gemm_bt<<<gg, 256, 0, stream>>>(vbf, wvb, bv, Vt,  nullptr, nullptr, N_TOK, DM, DM, 3);

  attn_kernel<<<512, 256, 0, stream>>>(qpj, Kn, Vt, qnw, apj);

  gemm_bt<<<gg, 256, 0, stream>>>(apj, wob, bo, nullptr, (float*)d_out, nullptr,
                                  N_TOK, DM, DM, 1);
}

// Round 4
// 180.984 us; speedup vs baseline: 2.4551x; 1.1191x over previous
//
#include <hip/hip_runtime.h>
#include <stdint.h>
#include <stddef.h>

#define N_TOK 4096
#define DM    1024
#define NHEAD 16
#define HD    64

typedef __attribute__((ext_vector_type(8)))  short bf16x8;
typedef __attribute__((ext_vector_type(4)))  short bf16x4;
typedef __attribute__((ext_vector_type(4)))  float f32x4;
typedef __attribute__((ext_vector_type(16))) float f32x16;

static __device__ __forceinline__ float bf2f(short u) {
  union { unsigned int i; float f; } c;
  c.i = ((unsigned int)(unsigned short)u) << 16;
  return c.f;
}
static __device__ __forceinline__ unsigned short f2bf(float f) {
  union { float f; unsigned int i; } c; c.f = f;
  unsigned int x = c.i;
  return (unsigned short)((x + 0x7fffu + ((x >> 16) & 1u)) >> 16);
}
static __device__ __forceinline__ unsigned int cvtpk(float lo, float hi) {
  unsigned int d;
  asm("v_cvt_pk_bf16_f32 %0, %1, %2" : "=v"(d) : "v"(lo), "v"(hi));
  return d;
}
static __device__ __forceinline__ void plswap(unsigned int& a, unsigned int& b) {
  asm("v_permlane32_swap_b32 %0, %1" : "+v"(a), "+v"(b));
}
#if __has_builtin(__builtin_amdgcn_exp2f)
#define EXP2(x) __builtin_amdgcn_exp2f(x)
#else
#define EXP2(x) exp2f(x)
#endif
// async global->LDS, 16B/lane; LDS dest wave-uniform base (HW adds lane*16)
static __device__ __forceinline__ void gload16(const void* g, void* l) {
  __builtin_amdgcn_global_load_lds(
      (const __attribute__((address_space(1))) unsigned int*)g,
      (__attribute__((address_space(3))) unsigned int*)l, 16, 0, 0);
}

// ---------------- fused fp32 -> bf16 conversion (all 7 tensors, 1 launch) ----------------
struct Cvt7 { const float* s[7]; unsigned short* d[7]; };
// units of 8 elems: segs 0..2 = 524288 each (q,k,v), 3..6 = 131072 each (weights)
__global__ void cvt_all(Cvt7 a) {
  int u0 = blockIdx.x << 10;              // 1024 units per block, uniform segment
  int seg, off;
  if (u0 < 1572864) { seg = u0 >> 19; off = u0 & 524287; }
  else { int j = u0 - 1572864; seg = 3 + (j >> 17); off = j & 131071; }
  const float* s = a.s[seg];
  unsigned short* dd = a.d[seg];
  int t = off + threadIdx.x;
#pragma unroll
  for (int j = 0; j < 4; ++j, t += 256) {
    const f32x4* sp = (const f32x4*)(s + (size_t)t * 8);
    f32x4 x = sp[0], y = sp[1];
    bf16x8 o;
    o[0] = (short)f2bf(x[0]); o[1] = (short)f2bf(x[1]);
    o[2] = (short)f2bf(x[2]); o[3] = (short)f2bf(x[3]);
    o[4] = (short)f2bf(y[0]); o[5] = (short)f2bf(y[1]);
    o[6] = (short)f2bf(y[2]); o[7] = (short)f2bf(y[3]);
    *(bf16x8*)(dd + (size_t)t * 8) = o;
  }
}

// ---------------- shared GEMM core: C = A @ W^T + bias, 64M x 128N, dbuf ----------------
// modes: 0 = bf16 row-major out; 1 = f32 row-major out;
//        2 = per-head RMSNorm -> Kn[h][n][64] bf16;  3 = transpose -> Vt[h][d][n] bf16
static __device__ __forceinline__ void gemm_core(
    const unsigned short* __restrict__ A,
    const unsigned short* __restrict__ W,
    const float* __restrict__ bias,
    unsigned short* __restrict__ Cb,
    float* __restrict__ Cf,
    const float* __restrict__ nw,
    int Nn, int K, int mode, int m0, int n0)
{
  __shared__ __align__(16) unsigned short At[2][64 * 32];    // 4KB per buf
  __shared__ __align__(16) unsigned short Wt[2][128 * 32];   // 8KB per buf
  const int tid  = threadIdx.x;
  const int wid  = tid >> 6, lane = tid & 63;
  const int lm   = lane & 15, lg = lane >> 4;
  const int wm   = (wid >> 1) * 32,  wn = (wid & 1) * 64;

  f32x4 acc[2][4];
#pragma unroll
  for (int i = 0; i < 2; ++i)
#pragma unroll
    for (int j = 0; j < 4; ++j) acc[i][j] = f32x4{0.f, 0.f, 0.f, 0.f};

  auto stage = [&](int b, int k0) {
#pragma unroll
    for (int i = 0; i < 3; ++i) {
      int c = wid * 3 + i;                 // 0..3 = A chunks, 4..11 = W chunks
      if (c < 4)
        gload16(A + (size_t)(m0 + c * 16 + (lane >> 2)) * K + k0 + (lane & 3) * 8,
                (char*)At + b * 4096 + c * 1024);
      else
        gload16(W + (size_t)(n0 + (c - 4) * 16 + (lane >> 2)) * K + k0 + (lane & 3) * 8,
                (char*)Wt + b * 8192 + (c - 4) * 1024);
    }
  };

  const int nk = K >> 5;
  stage(0, 0);
  __syncthreads();
  for (int kt = 0; kt < nk; ++kt) {
    const int cur = kt & 1;
    if (kt + 1 < nk) stage(cur ^ 1, (kt + 1) << 5);

    bf16x8 af[2], bfr[4];
#pragma unroll
    for (int mi = 0; mi < 2; ++mi)
      af[mi] = *(const bf16x8*)&At[cur][(wm + mi * 16 + lm) * 32 + lg * 8];
#pragma unroll
    for (int ni = 0; ni < 4; ++ni)
      bfr[ni] = *(const bf16x8*)&Wt[cur][(wn + ni * 16 + lm) * 32 + lg * 8];
    __builtin_amdgcn_s_setprio(1);
#pragma unroll
    for (int mi = 0; mi < 2; ++mi)
#pragma unroll
      for (int ni = 0; ni < 4; ++ni)
        acc[mi][ni] = __builtin_amdgcn_mfma_f32_16x16x32_bf16(
            af[mi], bfr[ni], acc[mi][ni], 0, 0, 0);
    __builtin_amdgcn_s_setprio(0);
    __syncthreads();
  }

  float bv[4];
#pragma unroll
  for (int ni = 0; ni < 4; ++ni) bv[ni] = bias[n0 + wn + ni * 16 + lm];

  if (mode <= 1) {
#pragma unroll
    for (int mi = 0; mi < 2; ++mi)
#pragma unroll
      for (int ni = 0; ni < 4; ++ni) {
        int n = n0 + wn + ni * 16 + lm;
#pragma unroll
        for (int r = 0; r < 4; ++r) {
          int m = m0 + wm + mi * 16 + lg * 4 + r;
          float v = acc[mi][ni][r] + bv[ni];
          if (mode == 1) Cf[(size_t)m * Nn + n] = v;
          else           Cb[(size_t)m * Nn + n] = f2bf(v);
        }
      }
  } else if (mode == 2) {
    // K path: wave's 64 cols = one full head; fused RMSNorm over d
    const int h = (n0 + wn) >> 6;
    float w_[4];
#pragma unroll
    for (int ni = 0; ni < 4; ++ni) w_[ni] = nw[ni * 16 + lm];
#pragma unroll
    for (int mi = 0; mi < 2; ++mi) {
      float t[4][4], ssq[4];
#pragma unroll
      for (int ni = 0; ni < 4; ++ni)
#pragma unroll
        for (int r = 0; r < 4; ++r) t[ni][r] = acc[mi][ni][r] + bv[ni];
#pragma unroll
      for (int r = 0; r < 4; ++r)
        ssq[r] = t[0][r]*t[0][r] + t[1][r]*t[1][r] + t[2][r]*t[2][r] + t[3][r]*t[3][r];
#pragma unroll
      for (int r = 0; r < 4; ++r) {
        ssq[r] += __shfl_xor(ssq[r], 1);
        ssq[r] += __shfl_xor(ssq[r], 2);
        ssq[r] += __shfl_xor(ssq[r], 4);
        ssq[r] += __shfl_xor(ssq[r], 8);
      }
#pragma unroll
      for (int r = 0; r < 4; ++r) {
        float iv = rsqrtf(ssq[r] * (1.f / 64.f) + 1e-5f);
        int n_ = m0 + wm + mi * 16 + lg * 4 + r;
#pragma unroll
        for (int ni = 0; ni < 4; ++ni) {
          int d = ni * 16 + lm;
          Cb[(size_t)h * (N_TOK * HD) + (size_t)n_ * HD + d] = f2bf(t[ni][r] * w_[ni] * iv);
        }
      }
    }
  } else {
    // V path: transpose to Vt[h][d][n]
    const int h = (n0 + wn) >> 6;
#pragma unroll
    for (int mi = 0; mi < 2; ++mi)
#pragma unroll
      for (int ni = 0; ni < 4; ++ni) {
        int d  = ni * 16 + lm;
        int nb = m0 + wm + mi * 16 + lg * 4;
        bf16x4 o;
#pragma unroll
        for (int r = 0; r < 4; ++r) o[r] = (short)f2bf(acc[mi][ni][r] + bv[ni]);
        *(bf16x4*)&Cb[(size_t)h * (HD * N_TOK) + (size_t)d * N_TOK + nb] = o;
      }
  }
}

// fused QKV projections: grid (8, 64, 3), z selects {q,k,v}
__global__ __launch_bounds__(256) void qkv_gemm(
    const unsigned short* __restrict__ a0, const unsigned short* __restrict__ a1,
    const unsigned short* __restrict__ a2,
    const unsigned short* __restrict__ w0, const unsigned short* __restrict__ w1,
    const unsigned short* __restrict__ w2,
    const float* __restrict__ b0, const float* __restrict__ b1,
    const float* __restrict__ b2,
    unsigned short* __restrict__ o0, unsigned short* __restrict__ o1,
    unsigned short* __restrict__ o2,
    const float* __restrict__ knw)
{
  const int z = blockIdx.z;
  const unsigned short* A = (z == 0) ? a0 : (z == 1) ? a1 : a2;
  const unsigned short* W = (z == 0) ? w0 : (z == 1) ? w1 : w2;
  const float* B          = (z == 0) ? b0 : (z == 1) ? b1 : b2;
  unsigned short* O       = (z == 0) ? o0 : (z == 1) ? o1 : o2;
  const int mode          = (z == 0) ? 0 : (z == 1) ? 2 : 3;
  gemm_core(A, W, B, O, nullptr, knw, DM, DM, mode,
            blockIdx.y * 64, blockIdx.x * 128);
}

// out-projection: f32 out
__global__ __launch_bounds__(256) void out_gemm(
    const unsigned short* __restrict__ A, const unsigned short* __restrict__ W,
    const float* __restrict__ bias, float* __restrict__ Cf)
{
  gemm_core(A, W, bias, nullptr, Cf, nullptr, DM, DM, 1,
            blockIdx.y * 64, blockIdx.x * 128);
}

// ---------------- fused RMSNorm(Q) + attention, swapped-QK 32x32, dbuf, kv-split 2 ----------------
#define CSUB 57.70780163555853f   // 40 * log2(e); |logit| <= 64 so exp2 arg <= 34.6
__global__ __launch_bounds__(256, 4) void attn_kernel(
    const unsigned short* __restrict__ qb,   // (n, 1024) bf16
    const unsigned short* __restrict__ kn,   // Kn[h][kv][64] bf16, normalized
    const unsigned short* __restrict__ vt,   // Vt[h][d][kv] bf16
    const float* __restrict__ wq,            // q_norm_w[64]
    float* __restrict__ opart,               // [2][4096][1024] f32 partial O
    float* __restrict__ lpart)               // [2][16][4096] f32 partial rowsum
{
  __shared__ __align__(16) unsigned short Kl[2][64 * 64];   // 8KB per buf
  __shared__ __align__(16) unsigned short Vl[2][64 * 64];

  // XCD-aware decode: grid 1024, XCD x owns heads {2x, 2x+1}, both kv-splits
  const int wg  = blockIdx.x;
  const int x_  = wg & 7, idx = wg >> 3;       // idx 0..127
  const int h   = x_ * 2 + (idx & 1);
  const int sp  = (idx >> 1) & 1;              // kv split half
  const int tid = threadIdx.x;
  const int wid = tid >> 6, lane = tid & 63;
  const int l31 = lane & 31, hi = lane >> 5;
  const int sl  = l31 & 7;
  const int qbase = (idx >> 2) * 128 + wid * 32;

  // ---- Q fragments, RMSNorm fused, scaled by log2(e) ----
  bf16x8 qf[4];
  {
    const unsigned short* qp = qb + (size_t)(qbase + l31) * DM + h * HD + hi * 8;
    float qv[32]; float ss = 0.f;
#pragma unroll
    for (int s = 0; s < 4; ++s) {
      bf16x8 raw = *(const bf16x8*)(qp + s * 16);
#pragma unroll
      for (int j = 0; j < 8; ++j) { float f = bf2f(raw[j]); qv[s*8+j] = f; ss += f*f; }
    }
    ss += __shfl_xor(ss, 32);
    float inv = rsqrtf(ss * (1.f / 64.f) + 1e-5f) * 1.44269504f;
#pragma unroll
    for (int s = 0; s < 4; ++s)
#pragma unroll
      for (int j = 0; j < 8; ++j)
        qf[s][j] = (short)f2bf(qv[s*8+j] * wq[s*16 + hi*8 + j] * inv);
  }

  int slot[4];
#pragma unroll
  for (int x = 0; x < 4; ++x) slot[x] = (((2*x + hi) ^ sl) << 4);
  const char* KlB = (const char*)Kl + l31 * 128;
  const char* VlB = (const char*)Vl + l31 * 128;

  // staging sources (pre-swizzled global addresses), 4 chunks/wave
  const char* gsrc[4];
  char*       ldst[4];
  long        gstep[4];
  {
    const char* knb = (const char*)kn + (size_t)h * (N_TOK * HD * 2);
    const char* vtb = (const char*)vt + (size_t)h * (HD * N_TOK * 2);
#pragma unroll
    for (int i = 0; i < 4; ++i) {
      int chunk = wid * 4 + i;           // 0..7 K, 8..15 V
      int off   = (chunk & 7) * 1024 + lane * 16;
      int row   = off >> 7;
      int scol  = (off & 127) ^ ((row & 7) << 4);
      if (chunk < 8) {
        gsrc[i]  = knb + (size_t)(sp * 2048 + row) * 128 + scol;
        gstep[i] = 64 * 128;
        ldst[i]  = (char*)Kl + (chunk & 7) * 1024;
      } else {
        gsrc[i]  = vtb + (size_t)row * (N_TOK * 2) + sp * 4096 + scol;
        gstep[i] = 64 * 2;
        ldst[i]  = (char*)Vl + (chunk & 7) * 1024;
      }
    }
  }

  f32x16 oacc[2], minit;
#pragma unroll
  for (int r = 0; r < 16; ++r) { oacc[0][r] = 0.f; oacc[1][r] = 0.f; minit[r] = -CSUB; }
  float lsp[4] = {0.f, 0.f, 0.f, 0.f};

  // prologue: stage tile 0 into buf 0
#pragma unroll
  for (int i = 0; i < 4; ++i) { gload16(gsrc[i], ldst[i]); gsrc[i] += gstep[i]; }
  __syncthreads();

  const int NT = 2048 / 64;   // 32 tiles per split half
  for (int it = 0; it < NT; ++it) {
    const int cur = it & 1;
    if (it + 1 < NT) {
      const int nb = cur ^ 1;
#pragma unroll
      for (int i = 0; i < 4; ++i) {
        gload16(gsrc[i], ldst[i] + (nb << 13));
        gsrc[i] += gstep[i];
      }
    }
    const char* KB = KlB + (cur << 13);
    const char* VB = VlB + (cur << 13);

#pragma unroll
    for (int kt = 0; kt < 2; ++kt) {
      // S^T = K Q^T over 32 kv x 32 q; C seeded with -CSUB (no movs)
      __builtin_amdgcn_s_setprio(1);
      bf16x8 kf0 = *(const bf16x8*)(KB + kt * 4096 + slot[0]);
      f32x16 sc = __builtin_amdgcn_mfma_f32_32x32x16_bf16(kf0, qf[0], minit, 0, 0, 0);
#pragma unroll
      for (int s = 1; s < 4; ++s) {
        bf16x8 kf = *(const bf16x8*)(KB + kt * 4096 + slot[s]);
        sc = __builtin_amdgcn_mfma_f32_32x32x16_bf16(kf, qf[s], sc, 0, 0, 0);
      }
      __builtin_amdgcn_s_setprio(0);
      float e[16];
#pragma unroll
      for (int r = 0; r < 16; ++r) { e[r] = EXP2(sc[r]); lsp[r & 3] += e[r]; }
      unsigned int wpk[4][2];
#pragma unroll
      for (int b = 0; b < 4; ++b) {
        wpk[b][0] = cvtpk(e[4*b+0], e[4*b+1]);
        wpk[b][1] = cvtpk(e[4*b+2], e[4*b+3]);
      }
#pragma unroll
      for (int pr = 0; pr < 2; ++pr) {
        unsigned int x0 = wpk[2*pr][0], x1 = wpk[2*pr][1];
        unsigned int y0 = wpk[2*pr+1][0], y1 = wpk[2*pr+1][1];
        plswap(x0, y0);
        plswap(x1, y1);
        union { unsigned int u[4]; bf16x8 v; } pa;
        pa.u[0] = x0; pa.u[1] = x1; pa.u[2] = y0; pa.u[3] = y1;
        int ks = kt * 2 + pr;
        __builtin_amdgcn_s_setprio(1);
#pragma unroll
        for (int dt = 0; dt < 2; ++dt) {
          bf16x8 vf = *(const bf16x8*)(VB + dt * 4096 + slot[ks]);
          oacc[dt] = __builtin_amdgcn_mfma_f32_32x32x16_bf16(pa.v, vf, oacc[dt], 0, 0, 0);
        }
        __builtin_amdgcn_s_setprio(0);
      }
    }
    __syncthreads();
  }

  // ---- epilogue: write f32 partials (no normalization; merge kernel divides) ----
  float ls = (lsp[0] + lsp[1]) + (lsp[2] + lsp[3]);
  ls += __shfl_xor(ls, 32);
  float* Op = opart + (size_t)sp * (N_TOK * DM);
#pragma unroll
  for (int r = 0; r < 16; ++r) {
    int q = (r & 3) + 8 * (r >> 2) + 4 * hi;
    float* p = Op + (size_t)(qbase + q) * DM + h * HD + l31;
    p[0]  = oacc[0][r];
    p[32] = oacc[1][r];
  }
  if (hi == 0)
    lpart[(size_t)sp * (NHEAD * N_TOK) + h * N_TOK + qbase + l31] = ls;
}

// ---------------- merge: apj = (O0 + O1) / (l0 + l1), bf16 ----------------
__global__ void merge_kernel(const float* __restrict__ opart,
                             const float* __restrict__ lpart,
                             unsigned short* __restrict__ am)
{
  int i = (blockIdx.x * 256 + threadIdx.x) * 8;   // 8 consecutive cols, same head
  int n = i >> 10, c = i & 1023, h = c >> 6;
  float l = lpart[h * N_TOK + n] + lpart[NHEAD * N_TOK + h * N_TOK + n];
  float il = 1.f / l;
  const f32x4* p0 = (const f32x4*)(opart + (size_t)n * DM + c);
  const f32x4* p1 = (const f32x4*)(opart + (size_t)(N_TOK * DM) + (size_t)n * DM + c);
  f32x4 a0 = p0[0], a1 = p0[1], b0_ = p1[0], b1_ = p1[1];
  bf16x8 o;
#pragma unroll
  for (int j = 0; j < 4; ++j) {
    o[j]     = (short)f2bf((a0[j] + b0_[j]) * il);
    o[j + 4] = (short)f2bf((a1[j] + b1_[j]) * il);
  }
  *(bf16x8*)(am + i) = o;
}

// ---------------- host ----------------
extern "C" void kernel_launch(void* const* d_in, const int* in_sizes, int n_in,
                              void* d_out, int out_size, void* d_ws, size_t ws_size,
                              hipStream_t stream) {
  const float* query = (const float*)d_in[0];
  const float* key   = (const float*)d_in[1];
  const float* value = (const float*)d_in[2];
  const float* Wq    = (const float*)d_in[3];
  const float* bq    = (const float*)d_in[4];
  const float* Wk    = (const float*)d_in[5];
  const float* bk    = (const float*)d_in[6];
  const float* Wv    = (const float*)d_in[7];
  const float* bv    = (const float*)d_in[8];
  const float* Wo    = (const float*)d_in[9];
  const float* bo    = (const float*)d_in[10];
  const float* qnw   = (const float*)d_in[11];
  const float* knw   = (const float*)d_in[12];

  char* ws = (char*)d_ws;
  const size_t MB = 1024 * 1024;
  // layout (MB): 0..8 qpj (reused as merge out) | 8..16 Kn | 16..24 Vt | 24..26 wob
  // 26..28 wqb | 28..30 wkb | 30..32 wvb | 32..40 qbf | 40..48 kbf | 48..56 vbf
  // during+after attn (inputs dead): 26..42 Opart0 | 42..58 Opart1 | 58..58.5 Lpart
  unsigned short* qpj = (unsigned short*)(ws + 0 * MB);
  unsigned short* Kn  = (unsigned short*)(ws + 8 * MB);
  unsigned short* Vt  = (unsigned short*)(ws + 16 * MB);
  unsigned short* wob = (unsigned short*)(ws + 24 * MB);
  unsigned short* wqb = (unsigned short*)(ws + 26 * MB);
  unsigned short* wkb = (unsigned short*)(ws + 28 * MB);
  unsigned short* wvb = (unsigned short*)(ws + 30 * MB);
  unsigned short* qbf = (unsigned short*)(ws + 32 * MB);
  unsigned short* kbf = (unsigned short*)(ws + 40 * MB);
  unsigned short* vbf = (unsigned short*)(ws + 48 * MB);
  float*          Op  = (float*)(ws + 26 * MB);
  float*          Lp  = (float*)(ws + 58 * MB);
  unsigned short* am  = qpj;   // merge output overwrites dead qpj

  Cvt7 ca;
  ca.s[0] = query; ca.d[0] = qbf;
  ca.s[1] = key;   ca.d[1] = kbf;
  ca.s[2] = value; ca.d[2] = vbf;
  ca.s[3] = Wq;    ca.d[3] = wqb;
  ca.s[4] = Wk;    ca.d[4] = wkb;
  ca.s[5] = Wv;    ca.d[5] = wvb;
  ca.s[6] = Wo;    ca.d[6] = wob;
  cvt_all<<<2048, 256, 0, stream>>>(ca);

  qkv_gemm<<<dim3(DM / 128, N_TOK / 64, 3), 256, 0, stream>>>(
      qbf, kbf, vbf, wqb, wkb, wvb, bq, bk, bv, qpj, Kn, Vt, knw);

  attn_kernel<<<1024, 256, 0, stream>>>(qpj, Kn, Vt, qnw, Op, Lp);

  merge_kernel<<<N_TOK * DM / 8 / 256, 256, 0, stream>>>(Op, Lp, am);

  out_gemm<<<dim3(DM / 128, N_TOK / 64), 256, 0, stream>>>(am, wob, bo, (float*)d_out);
}

// Round 5
// 154.724 us; speedup vs baseline: 2.8718x; 1.1697x over previous
//
#include <hip/hip_runtime.h>
#include <stdint.h>
#include <stddef.h>

#define N_TOK 4096
#define DM    1024
#define NHEAD 16
#define HD    64

typedef __attribute__((ext_vector_type(8)))  short bf16x8;
typedef __attribute__((ext_vector_type(4)))  short bf16x4;
typedef __attribute__((ext_vector_type(4)))  float f32x4;
typedef __attribute__((ext_vector_type(16))) float f32x16;

static __device__ __forceinline__ float bf2f(short u) {
  union { unsigned int i; float f; } c;
  c.i = ((unsigned int)(unsigned short)u) << 16;
  return c.f;
}
static __device__ __forceinline__ unsigned short f2bf(float f) {
  union { float f; unsigned int i; } c; c.f = f;
  unsigned int x = c.i;
  return (unsigned short)((x + 0x7fffu + ((x >> 16) & 1u)) >> 16);
}
static __device__ __forceinline__ unsigned int cvtpk(float lo, float hi) {
  unsigned int d;
  asm("v_cvt_pk_bf16_f32 %0, %1, %2" : "=v"(d) : "v"(lo), "v"(hi));
  return d;
}
static __device__ __forceinline__ void plswap(unsigned int& a, unsigned int& b) {
  asm("v_permlane32_swap_b32 %0, %1" : "+v"(a), "+v"(b));
}
#if __has_builtin(__builtin_amdgcn_exp2f)
#define EXP2(x) __builtin_amdgcn_exp2f(x)
#else
#define EXP2(x) exp2f(x)
#endif
// async global->LDS, 16B/lane; LDS dest wave-uniform base (HW adds lane*16)
static __device__ __forceinline__ void gload16(const void* g, void* l) {
  __builtin_amdgcn_global_load_lds(
      (const __attribute__((address_space(1))) unsigned int*)g,
      (__attribute__((address_space(3))) unsigned int*)l, 16, 0, 0);
}

// ---------------- fused fp32 -> bf16 conversion (all 7 tensors, 1 launch) ----------------
struct Cvt7 { const float* s[7]; unsigned short* d[7]; };
__global__ void cvt_all(Cvt7 a) {
  int u0 = blockIdx.x << 10;              // 1024 units per block, uniform segment
  int seg, off;
  if (u0 < 1572864) { seg = u0 >> 19; off = u0 & 524287; }
  else { int j = u0 - 1572864; seg = 3 + (j >> 17); off = j & 131071; }
  const float* s = a.s[seg];
  unsigned short* dd = a.d[seg];
  int t = off + threadIdx.x;
#pragma unroll
  for (int j = 0; j < 4; ++j, t += 256) {
    const f32x4* sp = (const f32x4*)(s + (size_t)t * 8);
    f32x4 x = sp[0], y = sp[1];
    bf16x8 o;
    o[0] = (short)f2bf(x[0]); o[1] = (short)f2bf(x[1]);
    o[2] = (short)f2bf(x[2]); o[3] = (short)f2bf(x[3]);
    o[4] = (short)f2bf(y[0]); o[5] = (short)f2bf(y[1]);
    o[6] = (short)f2bf(y[2]); o[7] = (short)f2bf(y[3]);
    *(bf16x8*)(dd + (size_t)t * 8) = o;
  }
}

// ---------------- GEMM core: C = A @ W^T + bias, (MI*32)M x 128N tile, dbuf ----------------
// modes: 0 = bf16 row-major out; 1 = f32 row-major out;
//        2 = per-head RMSNorm -> Kn[h][n][64] bf16;  3 = transpose -> Vt[h][d][n] bf16
template <int MI>
static __device__ __forceinline__ void gemm_core(
    const unsigned short* __restrict__ A,
    const unsigned short* __restrict__ W,
    const float* __restrict__ bias,
    unsigned short* __restrict__ Cb,
    float* __restrict__ Cf,
    const float* __restrict__ nw,
    int Nn, int K, int mode, int m0, int n0)
{
  __shared__ __align__(16) unsigned short At[2][MI * 1024];  // (MI*32) x 32
  __shared__ __align__(16) unsigned short Wt[2][128 * 32];
  const int tid  = threadIdx.x;
  const int wid  = tid >> 6, lane = tid & 63;
  const int lm   = lane & 15, lg = lane >> 4;
  const int wm   = (wid >> 1) * (MI * 16), wn = (wid & 1) * 64;
  const int CPW  = (MI * 2 + 8) / 4;       // chunks per wave

  f32x4 acc[MI][4];
#pragma unroll
  for (int i = 0; i < MI; ++i)
#pragma unroll
    for (int j = 0; j < 4; ++j) acc[i][j] = f32x4{0.f, 0.f, 0.f, 0.f};

  auto stage = [&](int b, int k0) {
#pragma unroll
    for (int i = 0; i < CPW; ++i) {
      int c = wid * CPW + i;
      if (c < MI * 2)
        gload16(A + (size_t)(m0 + c * 16 + (lane >> 2)) * K + k0 + (lane & 3) * 8,
                (char*)At + b * (MI * 2048) + c * 1024);
      else
        gload16(W + (size_t)(n0 + (c - MI * 2) * 16 + (lane >> 2)) * K + k0 + (lane & 3) * 8,
                (char*)Wt + b * 8192 + (c - MI * 2) * 1024);
    }
  };

  const int nk = K >> 5;
  stage(0, 0);
  __syncthreads();
  for (int kt = 0; kt < nk; ++kt) {
    const int cur = kt & 1;
    if (kt + 1 < nk) stage(cur ^ 1, (kt + 1) << 5);

    bf16x8 af[MI], bfr[4];
#pragma unroll
    for (int mi = 0; mi < MI; ++mi)
      af[mi] = *(const bf16x8*)&At[cur][(wm + mi * 16 + lm) * 32 + lg * 8];
#pragma unroll
    for (int ni = 0; ni < 4; ++ni)
      bfr[ni] = *(const bf16x8*)&Wt[cur][(wn + ni * 16 + lm) * 32 + lg * 8];
    __builtin_amdgcn_s_setprio(1);
#pragma unroll
    for (int mi = 0; mi < MI; ++mi)
#pragma unroll
      for (int ni = 0; ni < 4; ++ni)
        acc[mi][ni] = __builtin_amdgcn_mfma_f32_16x16x32_bf16(
            af[mi], bfr[ni], acc[mi][ni], 0, 0, 0);
    __builtin_amdgcn_s_setprio(0);
    __syncthreads();
  }

  float bv[4];
#pragma unroll
  for (int ni = 0; ni < 4; ++ni) bv[ni] = bias[n0 + wn + ni * 16 + lm];

  if (mode <= 1) {
#pragma unroll
    for (int mi = 0; mi < MI; ++mi)
#pragma unroll
      for (int ni = 0; ni < 4; ++ni) {
        int n = n0 + wn + ni * 16 + lm;
#pragma unroll
        for (int r = 0; r < 4; ++r) {
          int m = m0 + wm + mi * 16 + lg * 4 + r;
          float v = acc[mi][ni][r] + bv[ni];
          if (mode == 1) Cf[(size_t)m * Nn + n] = v;
          else           Cb[(size_t)m * Nn + n] = f2bf(v);
        }
      }
  } else if (mode == 2) {
    // K path: wave's 64 cols = one full head; fused RMSNorm over d
    const int h = (n0 + wn) >> 6;
    float w_[4];
#pragma unroll
    for (int ni = 0; ni < 4; ++ni) w_[ni] = nw[ni * 16 + lm];
#pragma unroll
    for (int mi = 0; mi < MI; ++mi) {
      float t[4][4], ssq[4];
#pragma unroll
      for (int ni = 0; ni < 4; ++ni)
#pragma unroll
        for (int r = 0; r < 4; ++r) t[ni][r] = acc[mi][ni][r] + bv[ni];
#pragma unroll
      for (int r = 0; r < 4; ++r)
        ssq[r] = t[0][r]*t[0][r] + t[1][r]*t[1][r] + t[2][r]*t[2][r] + t[3][r]*t[3][r];
#pragma unroll
      for (int r = 0; r < 4; ++r) {
        ssq[r] += __shfl_xor(ssq[r], 1);
        ssq[r] += __shfl_xor(ssq[r], 2);
        ssq[r] += __shfl_xor(ssq[r], 4);
        ssq[r] += __shfl_xor(ssq[r], 8);
      }
#pragma unroll
      for (int r = 0; r < 4; ++r) {
        float iv = rsqrtf(ssq[r] * (1.f / 64.f) + 1e-5f);
        int n_ = m0 + wm + mi * 16 + lg * 4 + r;
#pragma unroll
        for (int ni = 0; ni < 4; ++ni) {
          int d = ni * 16 + lm;
          Cb[(size_t)h * (N_TOK * HD) + (size_t)n_ * HD + d] = f2bf(t[ni][r] * w_[ni] * iv);
        }
      }
    }
  } else {
    // V path: transpose to Vt[h][d][n]
    const int h = (n0 + wn) >> 6;
#pragma unroll
    for (int mi = 0; mi < MI; ++mi)
#pragma unroll
      for (int ni = 0; ni < 4; ++ni) {
        int d  = ni * 16 + lm;
        int nb = m0 + wm + mi * 16 + lg * 4;
        bf16x4 o;
#pragma unroll
        for (int r = 0; r < 4; ++r) o[r] = (short)f2bf(acc[mi][ni][r] + bv[ni]);
        *(bf16x4*)&Cb[(size_t)h * (HD * N_TOK) + (size_t)d * N_TOK + nb] = o;
      }
  }
}

// fused QKV projections: grid (8, 32, 3), 128x128 tiles, z selects {q,k,v}
__global__ __launch_bounds__(256, 3) void qkv_gemm(
    const unsigned short* __restrict__ a0, const unsigned short* __restrict__ a1,
    const unsigned short* __restrict__ a2,
    const unsigned short* __restrict__ w0, const unsigned short* __restrict__ w1,
    const unsigned short* __restrict__ w2,
    const float* __restrict__ b0, const float* __restrict__ b1,
    const float* __restrict__ b2,
    unsigned short* __restrict__ o0, unsigned short* __restrict__ o1,
    unsigned short* __restrict__ o2,
    const float* __restrict__ knw)
{
  const int z = blockIdx.z;
  const unsigned short* A = (z == 0) ? a0 : (z == 1) ? a1 : a2;
  const unsigned short* W = (z == 0) ? w0 : (z == 1) ? w1 : w2;
  const float* B          = (z == 0) ? b0 : (z == 1) ? b1 : b2;
  unsigned short* O       = (z == 0) ? o0 : (z == 1) ? o1 : o2;
  const int mode          = (z == 0) ? 0 : (z == 1) ? 2 : 3;
  gemm_core<4>(A, W, B, O, nullptr, knw, DM, DM, mode,
               blockIdx.y * 128, blockIdx.x * 128);
}

// out-projection: f32 out, 64x128 tiles, grid (8, 64)
__global__ __launch_bounds__(256, 4) void out_gemm(
    const unsigned short* __restrict__ A, const unsigned short* __restrict__ W,
    const float* __restrict__ bias, float* __restrict__ Cf)
{
  gemm_core<2>(A, W, bias, nullptr, Cf, nullptr, DM, DM, 1,
               blockIdx.y * 64, blockIdx.x * 128);
}

// ---------------- fused RMSNorm(Q) + attention, swapped-QK 32x32, in-block kv-split ----------------
// grid 512 blocks x 512 threads. 8 waves = 2 kv-groups x 4 waves. q-tile 128/block.
// Softmax uses NO max-shift: uniform scale cancels in P/sum(P); args bounded (|s'|<=93).
__global__ __launch_bounds__(512, 4) void attn_kernel(
    const unsigned short* __restrict__ qb,   // (n, 1024) bf16
    const unsigned short* __restrict__ kn,   // Kn[h][kv][64] bf16, normalized
    const unsigned short* __restrict__ vt,   // Vt[h][d][kv] bf16
    const float* __restrict__ wq,            // q_norm_w[64]
    unsigned short* __restrict__ ob)         // (n, 1024) bf16
{
  // [group][buf][K/V][4096 bf16]: 64 KB total
  __shared__ __align__(16) unsigned short SM[2][2][2][4096];

  // XCD-aware decode: XCD x owns heads {2x, 2x+1}
  const int wg   = blockIdx.x;
  const int x_   = wg & 7, rest = wg >> 3;     // rest 0..63
  const int h    = x_ * 2 + (rest & 1);
  const int qt   = rest >> 1;                  // 0..31
  const int tid  = threadIdx.x;
  const int wid  = tid >> 6, lane = tid & 63;
  const int g    = wid >> 2, wv = wid & 3;
  const int l31  = lane & 31, hi = lane >> 5;
  const int sl   = l31 & 7;
  const int qbase = qt * 128 + wv * 32;

  // ---- Q fragments, RMSNorm fused, scaled by log2(e) ----
  bf16x8 qf[4];
  {
    const unsigned short* qp = qb + (size_t)(qbase + l31) * DM + h * HD + hi * 8;
    float qv[32]; float ss = 0.f;
#pragma unroll
    for (int s = 0; s < 4; ++s) {
      bf16x8 raw = *(const bf16x8*)(qp + s * 16);
#pragma unroll
      for (int j = 0; j < 8; ++j) { float f = bf2f(raw[j]); qv[s*8+j] = f; ss += f*f; }
    }
    ss += __shfl_xor(ss, 32);
    float inv = rsqrtf(ss * (1.f / 64.f) + 1e-5f) * 1.44269504f;
#pragma unroll
    for (int s = 0; s < 4; ++s)
#pragma unroll
      for (int j = 0; j < 8; ++j)
        qf[s][j] = (short)f2bf(qv[s*8+j] * wq[s*16 + hi*8 + j] * inv);
  }

  int slot[4];
#pragma unroll
  for (int x = 0; x < 4; ++x) slot[x] = (((2*x + hi) ^ sl) << 4);
  const char* base = (const char*)SM + g * 32768 + l31 * 128;

  // staging sources (pre-swizzled global addresses), 4 chunks/wave within group
  const char* gsrc[4];
  char*       ldst[4];
  long        gstep[4];
  {
    const char* knb = (const char*)kn + (size_t)h * (N_TOK * HD * 2);
    const char* vtb = (const char*)vt + (size_t)h * (HD * N_TOK * 2);
    char* smG = (char*)SM + g * 32768;   // buf 0 of this group
#pragma unroll
    for (int i = 0; i < 4; ++i) {
      int chunk = wv * 4 + i;            // 0..7 K, 8..15 V
      int off   = (chunk & 7) * 1024 + lane * 16;
      int row   = off >> 7;
      int scol  = (off & 127) ^ ((row & 7) << 4);
      if (chunk < 8) {
        gsrc[i]  = knb + (size_t)(g * 2048 + row) * 128 + scol;
        gstep[i] = 64 * 128;
        ldst[i]  = smG + (chunk & 7) * 1024;
      } else {
        gsrc[i]  = vtb + (size_t)row * (N_TOK * 2) + g * 4096 + scol;
        gstep[i] = 64 * 2;
        ldst[i]  = smG + 8192 + (chunk & 7) * 1024;
      }
    }
  }

  f32x16 oacc[2], fz;
#pragma unroll
  for (int r = 0; r < 16; ++r) { oacc[0][r] = 0.f; oacc[1][r] = 0.f; fz[r] = 0.f; }
  float lsp[4] = {0.f, 0.f, 0.f, 0.f};

  // prologue: stage tile 0 into buf 0
#pragma unroll
  for (int i = 0; i < 4; ++i) { gload16(gsrc[i], ldst[i]); gsrc[i] += gstep[i]; }
  __syncthreads();

  const int NT = 2048 / 64;
  for (int it = 0; it < NT; ++it) {
    const int cur = it & 1;
    if (it + 1 < NT) {
      const int nb = cur ^ 1;
#pragma unroll
      for (int i = 0; i < 4; ++i) {
        gload16(gsrc[i], ldst[i] + nb * 16384);
        gsrc[i] += gstep[i];
      }
    }
    const char* KB = base + cur * 16384;
    const char* VB = KB + 8192;

    // ---- both QK^T streams first (independent chains -> ILP) ----
    f32x16 sc[2];
    __builtin_amdgcn_s_setprio(1);
#pragma unroll
    for (int kt = 0; kt < 2; ++kt) {
      bf16x8 kf0 = *(const bf16x8*)(KB + kt * 4096 + slot[0]);
      sc[kt] = __builtin_amdgcn_mfma_f32_32x32x16_bf16(kf0, qf[0], fz, 0, 0, 0);
#pragma unroll
      for (int s = 1; s < 4; ++s) {
        bf16x8 kf = *(const bf16x8*)(KB + kt * 4096 + slot[s]);
        sc[kt] = __builtin_amdgcn_mfma_f32_32x32x16_bf16(kf, qf[s], sc[kt], 0, 0, 0);
      }
    }
    __builtin_amdgcn_s_setprio(0);

    // ---- per-kt: exp2 (no shift), pack, PV ----
#pragma unroll
    for (int kt = 0; kt < 2; ++kt) {
      float e[16];
#pragma unroll
      for (int r = 0; r < 16; ++r) { e[r] = EXP2(sc[kt][r]); lsp[r & 3] += e[r]; }
      unsigned int wpk[4][2];
#pragma unroll
      for (int b = 0; b < 4; ++b) {
        wpk[b][0] = cvtpk(e[4*b+0], e[4*b+1]);
        wpk[b][1] = cvtpk(e[4*b+2], e[4*b+3]);
      }
#pragma unroll
      for (int pr = 0; pr < 2; ++pr) {
        unsigned int x0 = wpk[2*pr][0], x1 = wpk[2*pr][1];
        unsigned int y0 = wpk[2*pr+1][0], y1 = wpk[2*pr+1][1];
        plswap(x0, y0);
        plswap(x1, y1);
        union { unsigned int u[4]; bf16x8 v; } pa;
        pa.u[0] = x0; pa.u[1] = x1; pa.u[2] = y0; pa.u[3] = y1;
        int ks = kt * 2 + pr;
        __builtin_amdgcn_s_setprio(1);
#pragma unroll
        for (int dt = 0; dt < 2; ++dt) {
          bf16x8 vf = *(const bf16x8*)(VB + dt * 4096 + slot[ks]);
          oacc[dt] = __builtin_amdgcn_mfma_f32_32x32x16_bf16(pa.v, vf, oacc[dt], 0, 0, 0);
        }
        __builtin_amdgcn_s_setprio(0);
      }
    }
    __syncthreads();
  }

  // ---- in-block merge of the two kv-groups via LDS, then bf16 write ----
  float ls = (lsp[0] + lsp[1]) + (lsp[2] + lsp[3]);
  ls += __shfl_xor(ls, 32);

  float* ex  = (float*)((char*)SM + 32768);   // 32 KB (group 1's region)
  float* lsx = (float*)SM;                    // 1 KB (group 0's region)
  const int idx = wv * 64 + lane;
  if (g == 1) {
#pragma unroll
    for (int dt = 0; dt < 2; ++dt)
#pragma unroll
      for (int r = 0; r < 16; ++r)
        ex[(dt * 16 + r) * 256 + idx] = oacc[dt][r];
    lsx[idx] = ls;
  }
  __syncthreads();
  if (g == 0) {
#pragma unroll
    for (int dt = 0; dt < 2; ++dt)
#pragma unroll
      for (int r = 0; r < 16; ++r)
        oacc[dt][r] += ex[(dt * 16 + r) * 256 + idx];
    ls += lsx[idx];
    float il = 1.f / ls;
#pragma unroll
    for (int r = 0; r < 16; ++r) {
      int q = (r & 3) + 8 * (r >> 2) + 4 * hi;
      float ilr = __int_as_float(
          __builtin_amdgcn_ds_bpermute(q << 2, __float_as_int(il)));
      unsigned short* op = ob + (size_t)(qbase + q) * DM + h * HD + l31;
      op[0]  = f2bf(oacc[0][r] * ilr);
      op[32] = f2bf(oacc[1][r] * ilr);
    }
  }
}

// ---------------- host ----------------
extern "C" void kernel_launch(void* const* d_in, const int* in_sizes, int n_in,
                              void* d_out, int out_size, void* d_ws, size_t ws_size,
                              hipStream_t stream) {
  const float* query = (const float*)d_in[0];
  const float* key   = (const float*)d_in[1];
  const float* value = (const float*)d_in[2];
  const float* Wq    = (const float*)d_in[3];
  const float* bq    = (const float*)d_in[4];
  const float* Wk    = (const float*)d_in[5];
  const float* bk    = (const float*)d_in[6];
  const float* Wv    = (const float*)d_in[7];
  const float* bv    = (const float*)d_in[8];
  const float* Wo    = (const float*)d_in[9];
  const float* bo    = (const float*)d_in[10];
  const float* qnw   = (const float*)d_in[11];
  const float* knw   = (const float*)d_in[12];

  char* ws = (char*)d_ws;
  const size_t MB = 1024 * 1024;
  unsigned short* qpj = (unsigned short*)(ws + 0 * MB);
  unsigned short* Kn  = (unsigned short*)(ws + 8 * MB);
  unsigned short* Vt  = (unsigned short*)(ws + 16 * MB);
  unsigned short* wob = (unsigned short*)(ws + 24 * MB);
  unsigned short* wqb = (unsigned short*)(ws + 26 * MB);
  unsigned short* wkb = (unsigned short*)(ws + 28 * MB);
  unsigned short* wvb = (unsigned short*)(ws + 30 * MB);
  unsigned short* qbf = (unsigned short*)(ws + 32 * MB);
  unsigned short* kbf = (unsigned short*)(ws + 40 * MB);
  unsigned short* vbf = (unsigned short*)(ws + 48 * MB);
  unsigned short* apj = (unsigned short*)(ws + 56 * MB);

  Cvt7 ca;
  ca.s[0] = query; ca.d[0] = qbf;
  ca.s[1] = key;   ca.d[1] = kbf;
  ca.s[2] = value; ca.d[2] = vbf;
  ca.s[3] = Wq;    ca.d[3] = wqb;
  ca.s[4] = Wk;    ca.d[4] = wkb;
  ca.s[5] = Wv;    ca.d[5] = wvb;
  ca.s[6] = Wo;    ca.d[6] = wob;
  cvt_all<<<2048, 256, 0, stream>>>(ca);

  qkv_gemm<<<dim3(DM / 128, N_TOK / 128, 3), 256, 0, stream>>>(
      qbf, kbf, vbf, wqb, wkb, wvb, bq, bk, bv, qpj, Kn, Vt, knw);

  attn_kernel<<<512, 512, 0, stream>>>(qpj, Kn, Vt, qnw, apj);

  out_gemm<<<dim3(DM / 128, N_TOK / 64), 256, 0, stream>>>(apj, wob, bo, (float*)d_out);
}